// Round 1
// baseline (1680.299 us; speedup 1.0000x reference)
//
#include <hip/hip_runtime.h>
#include <math.h>

#define NROWS 4096   // BATCH*SEQ
#define DM    1024   // D_MODEL
#define DI    2048   // D_INNER
#define DTR   64     // DT_RANK
#define DST   16     // D_STATE

// ---------------------------------------------------------------- LayerNorm
__global__ __launch_bounds__(256) void ln_kernel(const float* __restrict__ x,
                                                 const float* __restrict__ w,
                                                 const float* __restrict__ b,
                                                 float* __restrict__ xn) {
  const int row = blockIdx.x;
  const int tid = threadIdx.x;
  const float4 v = ((const float4*)(x + (size_t)row * DM))[tid];
  float s  = v.x + v.y + v.z + v.w;
  float ss = v.x * v.x + v.y * v.y + v.z * v.z + v.w * v.w;
  for (int off = 32; off > 0; off >>= 1) {
    s  += __shfl_down(s, off);
    ss += __shfl_down(ss, off);
  }
  __shared__ float red[4][2];
  if ((tid & 63) == 0) { red[tid >> 6][0] = s; red[tid >> 6][1] = ss; }
  __syncthreads();
  const float fs  = red[0][0] + red[1][0] + red[2][0] + red[3][0];
  const float fss = red[0][1] + red[1][1] + red[2][1] + red[3][1];
  const float mu  = fs * (1.f / DM);
  const float var = fss * (1.f / DM) - mu * mu;
  const float rs  = rsqrtf(var + 1e-5f);
  const float4 wv = ((const float4*)w)[tid];
  const float4 bv = ((const float4*)b)[tid];
  float4 o;
  o.x = (v.x - mu) * rs * wv.x + bv.x;
  o.y = (v.y - mu) * rs * wv.y + bv.y;
  o.z = (v.z - mu) * rs * wv.z + bv.z;
  o.w = (v.w - mu) * rs * wv.w + bv.w;
  ((float4*)(xn + (size_t)row * DM))[tid] = o;
}

// ---------------------------------------------------------------- helpers
__device__ __forceinline__ float softplus_f(float v) {
  return fmaxf(v, 0.f) + log1pf(__expf(-fabsf(v)));
}
__device__ __forceinline__ float silu_f(float v) {
  return v * (1.f / (1.f + __expf(-v)));
}

// ---------------------------------------------------------------- generic fp32 GEMM
// C[M,N] = A[M,K] @ B[K,N]; 64x64 tile, BK=16, 256 thr, 4x4 per thread.
// EPI: 0 none, 1 softplus(acc + bias[n]), 2 acc + resid[row*ldres+n]
// Assumes: M %64==0, K %16==0, N %4==0 (masked to N on B-load / C-store).
template <int EPI>
__global__ __launch_bounds__(256) void gemm_kernel(
    const float* __restrict__ A, const float* __restrict__ B,
    float* __restrict__ C, int M, int N, int K, int lda, int ldb, int ldc,
    const float* __restrict__ bias, const float* __restrict__ resid, int ldres) {
  __shared__ float As[64][20];  // padded: avoids 4-way bank conflict on a-reads
  __shared__ float Bs[16][64];
  const int tid = threadIdx.x;
  const int m0 = blockIdx.y * 64, n0 = blockIdx.x * 64;
  const int tx = tid & 15, ty = tid >> 4;
  const int am = tid >> 2, ak4 = (tid & 3) << 2;
  const int bk = tid >> 4, bn4 = (tid & 15) << 2;
  const bool bin = (n0 + bn4) < N;  // N%4==0 -> whole-vector validity
  float acc[4][4] = {};
  for (int k0 = 0; k0 < K; k0 += 16) {
    const float4 av = *(const float4*)&A[(size_t)(m0 + am) * lda + k0 + ak4];
    float4 bv = make_float4(0.f, 0.f, 0.f, 0.f);
    if (bin) bv = *(const float4*)&B[(size_t)(k0 + bk) * ldb + n0 + bn4];
    __syncthreads();  // previous tile's compute done
    *(float4*)&As[am][ak4] = av;
    *(float4*)&Bs[bk][bn4] = bv;
    __syncthreads();
#pragma unroll
    for (int k4 = 0; k4 < 4; k4++) {
      float4 aa[4], bb[4];
#pragma unroll
      for (int i = 0; i < 4; i++) aa[i] = *(const float4*)&As[ty * 4 + i][k4 * 4];
#pragma unroll
      for (int kk = 0; kk < 4; kk++) bb[kk] = *(const float4*)&Bs[k4 * 4 + kk][tx * 4];
#pragma unroll
      for (int kk = 0; kk < 4; kk++) {
#pragma unroll
        for (int i = 0; i < 4; i++) {
          const float a = (&aa[i].x)[kk];
          acc[i][0] += a * bb[kk].x;
          acc[i][1] += a * bb[kk].y;
          acc[i][2] += a * bb[kk].z;
          acc[i][3] += a * bb[kk].w;
        }
      }
    }
  }
#pragma unroll
  for (int i = 0; i < 4; i++) {
    const int row = m0 + ty * 4 + i;
    const int col = n0 + tx * 4;
    if (col < N) {
      float4 o = make_float4(acc[i][0], acc[i][1], acc[i][2], acc[i][3]);
      if (EPI == 1) {
        const float4 bi = *(const float4*)&bias[col];
        o.x = softplus_f(o.x + bi.x);
        o.y = softplus_f(o.y + bi.y);
        o.z = softplus_f(o.z + bi.z);
        o.w = softplus_f(o.w + bi.w);
      } else if (EPI == 2) {
        const float4 rv = *(const float4*)&resid[(size_t)row * ldres + col];
        o.x += rv.x; o.y += rv.y; o.z += rv.z; o.w += rv.w;
      }
      *(float4*)&C[(size_t)row * ldc + col] = o;
    }
  }
}

// ---------------------------------------------------------------- depthwise causal conv (D_CONV=4) + SiLU
// xi = xz[:, 0:2048] with row stride 4096. xc[r,d] = silu(sum_j xi[r-3+j,d]*w[d,j] + b[d])
__global__ __launch_bounds__(256) void conv_silu_kernel(const float* __restrict__ xz,
                                                        const float* __restrict__ cw,
                                                        const float* __restrict__ cb,
                                                        float* __restrict__ xc) {
  const int idx = blockIdx.x * 256 + threadIdx.x;  // 2M threads, 4 d's each
  const int d4 = (idx & 511) << 2;
  const int r = idx >> 9;
  const int t = r & 2047;
  const float4 w0 = *(const float4*)&cw[(d4 + 0) * 4];
  const float4 w1 = *(const float4*)&cw[(d4 + 1) * 4];
  const float4 w2 = *(const float4*)&cw[(d4 + 2) * 4];
  const float4 w3 = *(const float4*)&cw[(d4 + 3) * 4];
  float4 acc = *(const float4*)&cb[d4];
#pragma unroll
  for (int j = 0; j < 4; j++) {
    const int tj = t - 3 + j;
    if (tj >= 0) {
      const float4 xv = *(const float4*)&xz[(size_t)(r - 3 + j) * 4096 + d4];
      acc.x += xv.x * (&w0.x)[j];
      acc.y += xv.y * (&w1.x)[j];
      acc.z += xv.z * (&w2.x)[j];
      acc.w += xv.w * (&w3.x)[j];
    }
  }
  acc.x = silu_f(acc.x); acc.y = silu_f(acc.y);
  acc.z = silu_f(acc.z); acc.w = silu_f(acc.w);
  *(float4*)&xc[(size_t)r * DI + d4] = acc;
}

// ---------------------------------------------------------------- selective scan
// block = 256 thr = 16 groups of 16 lanes; group g handles channel d0+g, lane s = state.
// Time-chunked (T=64) LDS staging. y (=xc alias) gets full epilogue:
// y = (scan_y + xc*Dskip) * silu(z)
__global__ __launch_bounds__(256) void scan_kernel(
    const float* __restrict__ dt,   // ld 4096 (xz cols 0..2047)
    const float* __restrict__ xc,   // ld 2048
    const float* __restrict__ dbc,  // ld 96; B at +64, C at +80
    const float* __restrict__ A_log,
    const float* __restrict__ Dskip,
    const float* __restrict__ z,    // ld 4096 (xz cols 2048..4095)
    float* __restrict__ y) {        // ld 2048 (aliases xc; disjoint per block)
  const int b = blockIdx.x >> 7;
  const int d0 = (blockIdx.x & 127) * 16;
  const int tid = threadIdx.x;
  const int g = tid >> 4, s = tid & 15;
  const int d = d0 + g;
  const float A = -expf(A_log[d * DST + s]);
  float h = 0.f;
  __shared__ float sdt[64][16], su[64][16], sB[64][16], sC[64][16], sy[64][16];
  const int base_r = b * 2048;
  for (int t0 = 0; t0 < 2048; t0 += 64) {
    __syncthreads();  // previous writeback done before restage
#pragma unroll
    for (int i = 0; i < 4; i++) {
      const int flat = tid + i * 256;
      const int tt = flat >> 4, dd = flat & 15;
      const size_t r = base_r + t0 + tt;
      sdt[tt][dd] = dt[r * 4096 + d0 + dd];
      su[tt][dd]  = xc[r * 2048 + d0 + dd];
      sB[tt][dd]  = dbc[r * 96 + DTR + dd];
      sC[tt][dd]  = dbc[r * 96 + DTR + DST + dd];
    }
    __syncthreads();
    for (int tt = 0; tt < 64; tt++) {
      const float dtv = sdt[tt][g];
      const float uv  = su[tt][g];
      const float Bv  = sB[tt][s];
      const float Cv  = sC[tt][s];
      const float a = __expf(dtv * A);
      h = a * h + (dtv * uv) * Bv;
      float p = h * Cv;
      p += __shfl_xor(p, 8);
      p += __shfl_xor(p, 4);
      p += __shfl_xor(p, 2);
      p += __shfl_xor(p, 1);
      if (s == 0) sy[tt][g] = p;
    }
    __syncthreads();
#pragma unroll
    for (int i = 0; i < 4; i++) {
      const int flat = tid + i * 256;
      const int tt = flat >> 4, dd = flat & 15;
      const size_t r = base_r + t0 + tt;
      float yv = sy[tt][dd] + su[tt][dd] * Dskip[d0 + dd];
      const float zv = z[r * 4096 + d0 + dd];
      yv *= silu_f(zv);
      y[r * 2048 + d0 + dd] = yv;
    }
  }
}

// ---------------------------------------------------------------- launch
extern "C" void kernel_launch(void* const* d_in, const int* in_sizes, int n_in,
                              void* d_out, int out_size, void* d_ws, size_t ws_size,
                              hipStream_t stream) {
  const float* x         = (const float*)d_in[0];
  const float* ln_w      = (const float*)d_in[1];
  const float* ln_b      = (const float*)d_in[2];
  const float* in_proj_w = (const float*)d_in[3];
  const float* conv_w    = (const float*)d_in[4];
  const float* conv_b    = (const float*)d_in[5];
  const float* x_proj_w  = (const float*)d_in[6];
  const float* dt_proj_w = (const float*)d_in[7];
  const float* dt_proj_b = (const float*)d_in[8];
  const float* A_log     = (const float*)d_in[9];
  const float* D_skip    = (const float*)d_in[10];
  const float* out_proj_w= (const float*)d_in[11];
  float* out = (float*)d_out;
  float* ws  = (float*)d_ws;

  float* xn  = ws;                         // 4096*1024
  float* xz  = ws + 4194304;               // 4096*4096 (xi | z)
  float* xc  = ws + 4194304 + 16777216;    // 4096*2048
  float* dbc = xc + 8388608;               // 4096*96
  float* dtb = xz;                         // dt overwrites xi in place (ld 4096)
  float* zp  = xz + DI;                    // z (ld 4096)
  float* yb  = xc;                         // y overwrites xc (per-block disjoint)

  // 1. LayerNorm
  ln_kernel<<<NROWS, 256, 0, stream>>>(x, ln_w, ln_b, xn);
  // 2. in_proj: xz = xn @ W  (M=4096,N=4096,K=1024)
  gemm_kernel<0><<<dim3(64, 64), 256, 0, stream>>>(xn, in_proj_w, xz,
      NROWS, 4096, DM, DM, 4096, 4096, nullptr, nullptr, 0);
  // 3. depthwise conv + silu -> xc
  conv_silu_kernel<<<8192, 256, 0, stream>>>(xz, conv_w, conv_b, xc);
  // 4. x_proj: dbc = xc @ x_proj_w  (N=96, K=2048)
  gemm_kernel<0><<<dim3(2, 64), 256, 0, stream>>>(xc, x_proj_w, dbc,
      NROWS, 96, DI, DI, 96, 96, nullptr, nullptr, 0);
  // 5. dt_proj + softplus: dt = softplus(dbc[:, :64] @ dt_proj_w + b) (K=64)
  gemm_kernel<1><<<dim3(32, 64), 256, 0, stream>>>(dbc, dt_proj_w, dtb,
      NROWS, DI, DTR, 96, DI, 4096, dt_proj_b, nullptr, 0);
  // 6. selective scan (+ skip, * silu(z)) -> y
  scan_kernel<<<256, 256, 0, stream>>>(dtb, xc, dbc, A_log, D_skip, zp, yb);
  // 7. out_proj + residual: out = x + y @ out_proj_w  (N=1024, K=2048)
  gemm_kernel<2><<<dim3(16, 64), 256, 0, stream>>>(yb, out_proj_w, out,
      NROWS, DM, DI, DI, DM, DM, nullptr, x, DM);
}

// Round 2
// 1254.633 us; speedup vs baseline: 1.3393x; 1.3393x over previous
//
#include <hip/hip_runtime.h>
#include <math.h>

#define NROWS 4096   // BATCH*SEQ
#define DM    1024   // D_MODEL
#define DI    2048   // D_INNER
#define DTR   64     // DT_RANK
#define DST   16     // D_STATE
#define NCHUNK 16
#define CHLEN  128   // 2048 / NCHUNK

// ---------------------------------------------------------------- LayerNorm
__global__ __launch_bounds__(256) void ln_kernel(const float* __restrict__ x,
                                                 const float* __restrict__ w,
                                                 const float* __restrict__ b,
                                                 float* __restrict__ xn) {
  const int row = blockIdx.x;
  const int tid = threadIdx.x;
  const float4 v = ((const float4*)(x + (size_t)row * DM))[tid];
  float s  = v.x + v.y + v.z + v.w;
  float ss = v.x * v.x + v.y * v.y + v.z * v.z + v.w * v.w;
  for (int off = 32; off > 0; off >>= 1) {
    s  += __shfl_down(s, off);
    ss += __shfl_down(ss, off);
  }
  __shared__ float red[4][2];
  if ((tid & 63) == 0) { red[tid >> 6][0] = s; red[tid >> 6][1] = ss; }
  __syncthreads();
  const float fs  = red[0][0] + red[1][0] + red[2][0] + red[3][0];
  const float fss = red[0][1] + red[1][1] + red[2][1] + red[3][1];
  const float mu  = fs * (1.f / DM);
  const float var = fss * (1.f / DM) - mu * mu;
  const float rs  = rsqrtf(var + 1e-5f);
  const float4 wv = ((const float4*)w)[tid];
  const float4 bv = ((const float4*)b)[tid];
  float4 o;
  o.x = (v.x - mu) * rs * wv.x + bv.x;
  o.y = (v.y - mu) * rs * wv.y + bv.y;
  o.z = (v.z - mu) * rs * wv.z + bv.z;
  o.w = (v.w - mu) * rs * wv.w + bv.w;
  ((float4*)(xn + (size_t)row * DM))[tid] = o;
}

// ---------------------------------------------------------------- helpers
__device__ __forceinline__ float softplus_f(float v) {
  return fmaxf(v, 0.f) + log1pf(__expf(-fabsf(v)));
}
__device__ __forceinline__ float silu_f(float v) {
  return v * (1.f / (1.f + __expf(-v)));
}

// ---------------------------------------------------------------- generic fp32 GEMM
// C[M,N] = A[M,K] @ B[K,N]; 64x64 tile, BK=16, 256 thr, 4x4 per thread.
// EPI: 0 none, 1 softplus(acc + bias[n]), 2 acc + resid[row*ldres+n]
template <int EPI>
__global__ __launch_bounds__(256) void gemm_kernel(
    const float* __restrict__ A, const float* __restrict__ B,
    float* __restrict__ C, int M, int N, int K, int lda, int ldb, int ldc,
    const float* __restrict__ bias, const float* __restrict__ resid, int ldres) {
  __shared__ float As[64][20];
  __shared__ float Bs[16][64];
  const int tid = threadIdx.x;
  const int m0 = blockIdx.y * 64, n0 = blockIdx.x * 64;
  const int tx = tid & 15, ty = tid >> 4;
  const int am = tid >> 2, ak4 = (tid & 3) << 2;
  const int bk = tid >> 4, bn4 = (tid & 15) << 2;
  const bool bin = (n0 + bn4) < N;
  float acc[4][4] = {};
  for (int k0 = 0; k0 < K; k0 += 16) {
    const float4 av = *(const float4*)&A[(size_t)(m0 + am) * lda + k0 + ak4];
    float4 bv = make_float4(0.f, 0.f, 0.f, 0.f);
    if (bin) bv = *(const float4*)&B[(size_t)(k0 + bk) * ldb + n0 + bn4];
    __syncthreads();
    *(float4*)&As[am][ak4] = av;
    *(float4*)&Bs[bk][bn4] = bv;
    __syncthreads();
#pragma unroll
    for (int k4 = 0; k4 < 4; k4++) {
      float4 aa[4], bb[4];
#pragma unroll
      for (int i = 0; i < 4; i++) aa[i] = *(const float4*)&As[ty * 4 + i][k4 * 4];
#pragma unroll
      for (int kk = 0; kk < 4; kk++) bb[kk] = *(const float4*)&Bs[k4 * 4 + kk][tx * 4];
#pragma unroll
      for (int kk = 0; kk < 4; kk++) {
#pragma unroll
        for (int i = 0; i < 4; i++) {
          const float a = (&aa[i].x)[kk];
          acc[i][0] += a * bb[kk].x;
          acc[i][1] += a * bb[kk].y;
          acc[i][2] += a * bb[kk].z;
          acc[i][3] += a * bb[kk].w;
        }
      }
    }
  }
#pragma unroll
  for (int i = 0; i < 4; i++) {
    const int row = m0 + ty * 4 + i;
    const int col = n0 + tx * 4;
    if (col < N) {
      float4 o = make_float4(acc[i][0], acc[i][1], acc[i][2], acc[i][3]);
      if (EPI == 1) {
        const float4 bi = *(const float4*)&bias[col];
        o.x = softplus_f(o.x + bi.x);
        o.y = softplus_f(o.y + bi.y);
        o.z = softplus_f(o.z + bi.z);
        o.w = softplus_f(o.w + bi.w);
      } else if (EPI == 2) {
        const float4 rv = *(const float4*)&resid[(size_t)row * ldres + col];
        o.x += rv.x; o.y += rv.y; o.z += rv.z; o.w += rv.w;
      }
      *(float4*)&C[(size_t)row * ldc + col] = o;
    }
  }
}

// ---------------------------------------------------------------- depthwise causal conv (D_CONV=4) + SiLU
__global__ __launch_bounds__(256) void conv_silu_kernel(const float* __restrict__ xz,
                                                        const float* __restrict__ cw,
                                                        const float* __restrict__ cb,
                                                        float* __restrict__ xc) {
  const int idx = blockIdx.x * 256 + threadIdx.x;
  const int d4 = (idx & 511) << 2;
  const int r = idx >> 9;
  const int t = r & 2047;
  const float4 w0 = *(const float4*)&cw[(d4 + 0) * 4];
  const float4 w1 = *(const float4*)&cw[(d4 + 1) * 4];
  const float4 w2 = *(const float4*)&cw[(d4 + 2) * 4];
  const float4 w3 = *(const float4*)&cw[(d4 + 3) * 4];
  float4 acc = *(const float4*)&cb[d4];
#pragma unroll
  for (int j = 0; j < 4; j++) {
    const int tj = t - 3 + j;
    if (tj >= 0) {
      const float4 xv = *(const float4*)&xz[(size_t)(r - 3 + j) * 4096 + d4];
      acc.x += xv.x * (&w0.x)[j];
      acc.y += xv.y * (&w1.x)[j];
      acc.z += xv.z * (&w2.x)[j];
      acc.w += xv.w * (&w3.x)[j];
    }
  }
  acc.x = silu_f(acc.x); acc.y = silu_f(acc.y);
  acc.z = silu_f(acc.z); acc.w = silu_f(acc.w);
  *(float4*)&xc[(size_t)r * DI + d4] = acc;
}

// ---------------------------------------------------------------- chunked selective scan
// grid: 2(b) x 128(dgroup) x 16(chunk).  block: 16 groups of 16 lanes.
// pass1: local scan with h_in=0 -> store aprod (decay product) + hout per state.
__global__ __launch_bounds__(256) void scan_pass1(
    const float* __restrict__ dt,   // ld 4096
    const float* __restrict__ xc,   // ld 2048
    const float* __restrict__ dbc,  // ld 96; B at +64
    const float* __restrict__ A_log,
    float* __restrict__ aprod_buf, float* __restrict__ hout_buf) {
  const int b  = blockIdx.x >> 11;
  const int dg = (blockIdx.x >> 4) & 127;
  const int c  = blockIdx.x & 15;
  const int d0 = dg * 16;
  const int tid = threadIdx.x;
  const int g = tid >> 4, s = tid & 15;
  const float A = -expf(A_log[(d0 + g) * DST + s]);
  float h = 0.f, ap = 1.f;
  __shared__ float sdt[64][16], su[64][16], sB[64][16];
  const int base_r = b * 2048 + c * CHLEN;
  for (int t0 = 0; t0 < CHLEN; t0 += 64) {
    __syncthreads();
#pragma unroll
    for (int i = 0; i < 4; i++) {
      const int flat = tid + i * 256;
      const int tt = flat >> 4, dd = flat & 15;
      const size_t r = base_r + t0 + tt;
      sdt[tt][dd] = dt[r * 4096 + d0 + dd];
      su[tt][dd]  = xc[r * 2048 + d0 + dd];
      sB[tt][dd]  = dbc[r * 96 + DTR + dd];
    }
    __syncthreads();
#pragma unroll 8
    for (int tt = 0; tt < 64; tt++) {
      const float dtv = sdt[tt][g];
      const float a = __expf(dtv * A);
      h = a * h + (dtv * su[tt][g]) * sB[tt][s];
      ap *= a;
    }
  }
  const int idx = ((b * 128 + dg) * NCHUNK + c) * 256 + tid;
  aprod_buf[idx] = ap;
  hout_buf[idx]  = h;
}

// fixup: per (b,dgroup,g,s) fold 16 chunk carries -> per-chunk h_in (overwrites hout_buf)
__global__ __launch_bounds__(256) void scan_fixup(const float* __restrict__ aprod_buf,
                                                  float* __restrict__ hout_buf) {
  const int t = blockIdx.x * 256 + threadIdx.x;  // 65536
  const int seq = t >> 8;
  const int lane = t & 255;
  const int base = seq * NCHUNK * 256 + lane;
  float h = 0.f;
#pragma unroll
  for (int c = 0; c < NCHUNK; c++) {
    const float a = aprod_buf[base + c * 256];
    const float o = hout_buf[base + c * 256];
    hout_buf[base + c * 256] = h;   // h_in for chunk c
    h = a * h + o;
  }
}

// pass2: re-run chunk from h_in, full epilogue: y = (scan_y + xc*Dskip) * silu(z)
__global__ __launch_bounds__(256) void scan_pass2(
    const float* __restrict__ dt, const float* __restrict__ xc,
    const float* __restrict__ dbc, const float* __restrict__ A_log,
    const float* __restrict__ Dskip, const float* __restrict__ z,
    const float* __restrict__ hin_buf, float* __restrict__ y) {
  const int b  = blockIdx.x >> 11;
  const int dg = (blockIdx.x >> 4) & 127;
  const int c  = blockIdx.x & 15;
  const int d0 = dg * 16;
  const int tid = threadIdx.x;
  const int g = tid >> 4, s = tid & 15;
  const float A = -expf(A_log[(d0 + g) * DST + s]);
  float h = hin_buf[((b * 128 + dg) * NCHUNK + c) * 256 + tid];
  __shared__ float sdt[64][16], su[64][16], sB[64][16], sC[64][16], sy[64][16];
  const int base_r = b * 2048 + c * CHLEN;
  for (int t0 = 0; t0 < CHLEN; t0 += 64) {
    __syncthreads();
#pragma unroll
    for (int i = 0; i < 4; i++) {
      const int flat = tid + i * 256;
      const int tt = flat >> 4, dd = flat & 15;
      const size_t r = base_r + t0 + tt;
      sdt[tt][dd] = dt[r * 4096 + d0 + dd];
      su[tt][dd]  = xc[r * 2048 + d0 + dd];
      sB[tt][dd]  = dbc[r * 96 + DTR + dd];
      sC[tt][dd]  = dbc[r * 96 + DTR + DST + dd];
    }
    __syncthreads();
#pragma unroll 4
    for (int tt = 0; tt < 64; tt++) {
      const float dtv = sdt[tt][g];
      const float a = __expf(dtv * A);
      h = a * h + (dtv * su[tt][g]) * sB[tt][s];
      float p = h * sC[tt][s];
      p += __shfl_xor(p, 8);
      p += __shfl_xor(p, 4);
      p += __shfl_xor(p, 2);
      p += __shfl_xor(p, 1);
      if (s == 0) sy[tt][g] = p;
    }
    __syncthreads();
#pragma unroll
    for (int i = 0; i < 4; i++) {
      const int flat = tid + i * 256;
      const int tt = flat >> 4, dd = flat & 15;
      const size_t r = base_r + t0 + tt;
      float yv = sy[tt][dd] + su[tt][dd] * Dskip[d0 + dd];
      const float zv = z[r * 4096 + d0 + dd];
      yv *= silu_f(zv);
      y[r * 2048 + d0 + dd] = yv;
    }
  }
}

// ---------------------------------------------------------------- launch
extern "C" void kernel_launch(void* const* d_in, const int* in_sizes, int n_in,
                              void* d_out, int out_size, void* d_ws, size_t ws_size,
                              hipStream_t stream) {
  const float* x         = (const float*)d_in[0];
  const float* ln_w      = (const float*)d_in[1];
  const float* ln_b      = (const float*)d_in[2];
  const float* in_proj_w = (const float*)d_in[3];
  const float* conv_w    = (const float*)d_in[4];
  const float* conv_b    = (const float*)d_in[5];
  const float* x_proj_w  = (const float*)d_in[6];
  const float* dt_proj_w = (const float*)d_in[7];
  const float* dt_proj_b = (const float*)d_in[8];
  const float* A_log     = (const float*)d_in[9];
  const float* D_skip    = (const float*)d_in[10];
  const float* out_proj_w= (const float*)d_in[11];
  float* out = (float*)d_out;
  float* ws  = (float*)d_ws;

  float* xn  = ws;                         // 4096*1024 (dead after in_proj)
  float* xz  = ws + 4194304;               // 4096*4096 (xi | z)
  float* xc  = ws + 4194304 + 16777216;    // 4096*2048
  float* dbc = xc + 8388608;               // 4096*96
  float* dtb = xz;                         // dt overwrites xi in place (ld 4096)
  float* zp  = xz + DI;                    // z (ld 4096)
  float* yb  = xc;                         // y overwrites xc (per-block disjoint)
  float* aprod = xn;                       // carries reuse dead xn: 1M floats
  float* hout  = xn + (1 << 20);           // 1M floats

  // 1. LayerNorm
  ln_kernel<<<NROWS, 256, 0, stream>>>(x, ln_w, ln_b, xn);
  // 2. in_proj: xz = xn @ W  (M=4096,N=4096,K=1024)
  gemm_kernel<0><<<dim3(64, 64), 256, 0, stream>>>(xn, in_proj_w, xz,
      NROWS, 4096, DM, DM, 4096, 4096, nullptr, nullptr, 0);
  // 3. depthwise conv + silu -> xc
  conv_silu_kernel<<<8192, 256, 0, stream>>>(xz, conv_w, conv_b, xc);
  // 4. x_proj: dbc = xc @ x_proj_w  (N=96, K=2048)
  gemm_kernel<0><<<dim3(2, 64), 256, 0, stream>>>(xc, x_proj_w, dbc,
      NROWS, 96, DI, DI, 96, 96, nullptr, nullptr, 0);
  // 5. dt_proj + softplus: dt = softplus(dbc[:, :64] @ dt_proj_w + b) (K=64)
  gemm_kernel<1><<<dim3(32, 64), 256, 0, stream>>>(dbc, dt_proj_w, dtb,
      NROWS, DI, DTR, 96, DI, 4096, dt_proj_b, nullptr, 0);
  // 6. chunked selective scan
  scan_pass1<<<4096, 256, 0, stream>>>(dtb, xc, dbc, A_log, aprod, hout);
  scan_fixup<<<256, 256, 0, stream>>>(aprod, hout);
  scan_pass2<<<4096, 256, 0, stream>>>(dtb, xc, dbc, A_log, D_skip, zp, hout, yb);
  // 7. out_proj + residual: out = x + y @ out_proj_w  (N=1024, K=2048)
  gemm_kernel<2><<<dim3(16, 64), 256, 0, stream>>>(yb, out_proj_w, out,
      NROWS, DM, DI, DI, DM, DM, nullptr, x, DM);
}

// Round 3
// 594.550 us; speedup vs baseline: 2.8262x; 2.1102x over previous
//
#include <hip/hip_runtime.h>
#include <math.h>

#define NROWS 4096   // BATCH*SEQ
#define DM    1024   // D_MODEL
#define DI    2048   // D_INNER
#define DTR   64     // DT_RANK
#define DST   16     // D_STATE
#define NCHUNK 16
#define CHLEN  128   // 2048 / NCHUNK

typedef __attribute__((ext_vector_type(8))) short bf16x8;
typedef __attribute__((ext_vector_type(4))) float f32x4;

__device__ __forceinline__ unsigned short f2bf(float f) {
  unsigned u = __float_as_uint(f);
  u = (u + 0x7fffu + ((u >> 16) & 1u)) >> 16;   // RNE
  return (unsigned short)u;
}
__device__ __forceinline__ float softplus_f(float v) {
  return fmaxf(v, 0.f) + log1pf(__expf(-fabsf(v)));
}
__device__ __forceinline__ float silu_f(float v) {
  return v * (1.f / (1.f + __expf(-v)));
}
__device__ __forceinline__ void gload_lds16(const void* g, void* l) {
  __builtin_amdgcn_global_load_lds(
      (const __attribute__((address_space(1))) void*)g,
      (__attribute__((address_space(3))) void*)l, 16, 0, 0);
}

// ---------------------------------------------------------------- LayerNorm -> bf16
__global__ __launch_bounds__(256) void ln_kernel(const float* __restrict__ x,
                                                 const float* __restrict__ w,
                                                 const float* __restrict__ b,
                                                 unsigned short* __restrict__ xnb) {
  const int row = blockIdx.x;
  const int tid = threadIdx.x;
  const float4 v = ((const float4*)(x + (size_t)row * DM))[tid];
  float s  = v.x + v.y + v.z + v.w;
  float ss = v.x * v.x + v.y * v.y + v.z * v.z + v.w * v.w;
  for (int off = 32; off > 0; off >>= 1) {
    s  += __shfl_down(s, off);
    ss += __shfl_down(ss, off);
  }
  __shared__ float red[4][2];
  if ((tid & 63) == 0) { red[tid >> 6][0] = s; red[tid >> 6][1] = ss; }
  __syncthreads();
  const float fs  = red[0][0] + red[1][0] + red[2][0] + red[3][0];
  const float fss = red[0][1] + red[1][1] + red[2][1] + red[3][1];
  const float mu  = fs * (1.f / DM);
  const float var = fss * (1.f / DM) - mu * mu;
  const float rs  = rsqrtf(var + 1e-5f);
  const float4 wv = ((const float4*)w)[tid];
  const float4 bv = ((const float4*)b)[tid];
  ushort4 o;
  o.x = f2bf((v.x - mu) * rs * wv.x + bv.x);
  o.y = f2bf((v.y - mu) * rs * wv.y + bv.y);
  o.z = f2bf((v.z - mu) * rs * wv.z + bv.z);
  o.w = f2bf((v.w - mu) * rs * wv.w + bv.w);
  ((ushort4*)(xnb + (size_t)row * DM))[tid] = o;
}

// ---------------------------------------------------------------- W[K][N] f32 -> Wt[N][K] bf16
__global__ __launch_bounds__(256) void transpose_bf16(const float* __restrict__ W,
                                                      unsigned short* __restrict__ Wt,
                                                      int K, int N) {
  __shared__ float t[32][33];
  const int n0 = blockIdx.x * 32, k0 = blockIdx.y * 32;
  const int tx = threadIdx.x & 31, ty = threadIdx.x >> 5;  // ty 0..7
#pragma unroll
  for (int i = 0; i < 4; i++)
    t[ty + i * 8][tx] = W[(size_t)(k0 + ty + i * 8) * N + n0 + tx];
  __syncthreads();
#pragma unroll
  for (int i = 0; i < 4; i++)
    Wt[(size_t)(n0 + ty + i * 8) * K + k0 + tx] = f2bf(t[tx][ty + i * 8]);
}

// ---------------------------------------------------------------- bf16 MFMA GEMM
// C[M,N] = A[M,K](bf16) @ Bt[N,K](bf16)^T; 128x128 tile, BK=32, 4 waves 2x2.
// EPI: 0 none, 2 acc + resid[row*N+col]
template <int EPI>
__global__ __launch_bounds__(256) void gemm_mfma(
    const unsigned short* __restrict__ A, const unsigned short* __restrict__ Bt,
    float* __restrict__ C, int M, int N, int K, const float* __restrict__ resid) {
  __shared__ unsigned short Asl[128 * 32];
  __shared__ unsigned short Bsl[128 * 32];
  const int tid  = threadIdx.x;
  const int wave = tid >> 6, lane = tid & 63;
  const int wr = wave >> 1, wc = wave & 1;
  const int m0 = blockIdx.y * 128, n0 = blockIdx.x * 128;
  const int srow = lane >> 2;            // 0..15 within chunk
  const int skoff = (lane & 3) * 8;      // 0,8,16,24
  f32x4 acc[4][4] = {};
  for (int k0 = 0; k0 < K; k0 += 32) {
    __syncthreads();
#pragma unroll
    for (int i = 0; i < 2; i++) {
      const int c = wave * 2 + i;        // chunk 0..7 (16 rows each)
      gload_lds16(A  + (size_t)(m0 + c * 16 + srow) * K + k0 + skoff, &Asl[c * 512]);
      gload_lds16(Bt + (size_t)(n0 + c * 16 + srow) * K + k0 + skoff, &Bsl[c * 512]);
    }
    __syncthreads();
    bf16x8 af[4], bfr[4];
#pragma unroll
    for (int m = 0; m < 4; m++)
      af[m] = *(const bf16x8*)&Asl[(wr * 64 + m * 16 + (lane & 15)) * 32 + (lane >> 4) * 8];
#pragma unroll
    for (int n = 0; n < 4; n++)
      bfr[n] = *(const bf16x8*)&Bsl[(wc * 64 + n * 16 + (lane & 15)) * 32 + (lane >> 4) * 8];
#pragma unroll
    for (int m = 0; m < 4; m++)
#pragma unroll
      for (int n = 0; n < 4; n++)
        acc[m][n] = __builtin_amdgcn_mfma_f32_16x16x32_bf16(af[m], bfr[n], acc[m][n], 0, 0, 0);
  }
#pragma unroll
  for (int m = 0; m < 4; m++) {
#pragma unroll
    for (int n = 0; n < 4; n++) {
      const int col = n0 + wc * 64 + n * 16 + (lane & 15);
#pragma unroll
      for (int r = 0; r < 4; r++) {
        const int row = m0 + wr * 64 + m * 16 + (lane >> 4) * 4 + r;
        float v = acc[m][n][r];
        if (EPI == 2) v += resid[(size_t)row * N + col];
        C[(size_t)row * N + col] = v;
      }
    }
  }
}

// ---------------------------------------------------------------- generic fp32 GEMM (x_proj / dt_proj)
template <int EPI>  // 0 none, 1 softplus(acc + bias[n])
__global__ __launch_bounds__(256) void gemm_kernel(
    const float* __restrict__ A, const float* __restrict__ B,
    float* __restrict__ C, int M, int N, int K, int lda, int ldb, int ldc,
    const float* __restrict__ bias) {
  __shared__ float As[64][20];
  __shared__ float Bs[16][64];
  const int tid = threadIdx.x;
  const int m0 = blockIdx.y * 64, n0 = blockIdx.x * 64;
  const int tx = tid & 15, ty = tid >> 4;
  const int am = tid >> 2, ak4 = (tid & 3) << 2;
  const int bk = tid >> 4, bn4 = (tid & 15) << 2;
  const bool bin = (n0 + bn4) < N;
  float acc[4][4] = {};
  for (int k0 = 0; k0 < K; k0 += 16) {
    const float4 av = *(const float4*)&A[(size_t)(m0 + am) * lda + k0 + ak4];
    float4 bv = make_float4(0.f, 0.f, 0.f, 0.f);
    if (bin) bv = *(const float4*)&B[(size_t)(k0 + bk) * ldb + n0 + bn4];
    __syncthreads();
    *(float4*)&As[am][ak4] = av;
    *(float4*)&Bs[bk][bn4] = bv;
    __syncthreads();
#pragma unroll
    for (int k4 = 0; k4 < 4; k4++) {
      float4 aa[4], bb[4];
#pragma unroll
      for (int i = 0; i < 4; i++) aa[i] = *(const float4*)&As[ty * 4 + i][k4 * 4];
#pragma unroll
      for (int kk = 0; kk < 4; kk++) bb[kk] = *(const float4*)&Bs[k4 * 4 + kk][tx * 4];
#pragma unroll
      for (int kk = 0; kk < 4; kk++) {
#pragma unroll
        for (int i = 0; i < 4; i++) {
          const float a = (&aa[i].x)[kk];
          acc[i][0] += a * bb[kk].x;
          acc[i][1] += a * bb[kk].y;
          acc[i][2] += a * bb[kk].z;
          acc[i][3] += a * bb[kk].w;
        }
      }
    }
  }
#pragma unroll
  for (int i = 0; i < 4; i++) {
    const int row = m0 + ty * 4 + i;
    const int col = n0 + tx * 4;
    if (col < N) {
      float4 o = make_float4(acc[i][0], acc[i][1], acc[i][2], acc[i][3]);
      if (EPI == 1) {
        const float4 bi = *(const float4*)&bias[col];
        o.x = softplus_f(o.x + bi.x);
        o.y = softplus_f(o.y + bi.y);
        o.z = softplus_f(o.z + bi.z);
        o.w = softplus_f(o.w + bi.w);
      }
      *(float4*)&C[(size_t)row * ldc + col] = o;
    }
  }
}

// ---------------------------------------------------------------- depthwise causal conv (D_CONV=4) + SiLU
__global__ __launch_bounds__(256) void conv_silu_kernel(const float* __restrict__ xz,
                                                        const float* __restrict__ cw,
                                                        const float* __restrict__ cb,
                                                        float* __restrict__ xc) {
  const int idx = blockIdx.x * 256 + threadIdx.x;
  const int d4 = (idx & 511) << 2;
  const int r = idx >> 9;
  const int t = r & 2047;
  const float4 w0 = *(const float4*)&cw[(d4 + 0) * 4];
  const float4 w1 = *(const float4*)&cw[(d4 + 1) * 4];
  const float4 w2 = *(const float4*)&cw[(d4 + 2) * 4];
  const float4 w3 = *(const float4*)&cw[(d4 + 3) * 4];
  float4 acc = *(const float4*)&cb[d4];
#pragma unroll
  for (int j = 0; j < 4; j++) {
    const int tj = t - 3 + j;
    if (tj >= 0) {
      const float4 xv = *(const float4*)&xz[(size_t)(r - 3 + j) * 4096 + d4];
      acc.x += xv.x * (&w0.x)[j];
      acc.y += xv.y * (&w1.x)[j];
      acc.z += xv.z * (&w2.x)[j];
      acc.w += xv.w * (&w3.x)[j];
    }
  }
  acc.x = silu_f(acc.x); acc.y = silu_f(acc.y);
  acc.z = silu_f(acc.z); acc.w = silu_f(acc.w);
  *(float4*)&xc[(size_t)r * DI + d4] = acc;
}

// ---------------------------------------------------------------- chunked selective scan
__global__ __launch_bounds__(256) void scan_pass1(
    const float* __restrict__ dt, const float* __restrict__ xc,
    const float* __restrict__ dbc, const float* __restrict__ A_log,
    float* __restrict__ aprod_buf, float* __restrict__ hout_buf) {
  const int b  = blockIdx.x >> 11;
  const int dg = (blockIdx.x >> 4) & 127;
  const int c  = blockIdx.x & 15;
  const int d0 = dg * 16;
  const int tid = threadIdx.x;
  const int g = tid >> 4, s = tid & 15;
  const float A = -expf(A_log[(d0 + g) * DST + s]);
  float h = 0.f, ap = 1.f;
  __shared__ float sdt[64][16], su[64][16], sB[64][16];
  const int base_r = b * 2048 + c * CHLEN;
  for (int t0 = 0; t0 < CHLEN; t0 += 64) {
    __syncthreads();
#pragma unroll
    for (int i = 0; i < 4; i++) {
      const int flat = tid + i * 256;
      const int tt = flat >> 4, dd = flat & 15;
      const size_t r = base_r + t0 + tt;
      sdt[tt][dd] = dt[r * 4096 + d0 + dd];
      su[tt][dd]  = xc[r * 2048 + d0 + dd];
      sB[tt][dd]  = dbc[r * 96 + DTR + dd];
    }
    __syncthreads();
#pragma unroll 8
    for (int tt = 0; tt < 64; tt++) {
      const float dtv = sdt[tt][g];
      const float a = __expf(dtv * A);
      h = a * h + (dtv * su[tt][g]) * sB[tt][s];
      ap *= a;
    }
  }
  const int idx = ((b * 128 + dg) * NCHUNK + c) * 256 + tid;
  aprod_buf[idx] = ap;
  hout_buf[idx]  = h;
}

__global__ __launch_bounds__(256) void scan_fixup(const float* __restrict__ aprod_buf,
                                                  float* __restrict__ hout_buf) {
  const int t = blockIdx.x * 256 + threadIdx.x;
  const int seq = t >> 8;
  const int lane = t & 255;
  const int base = seq * NCHUNK * 256 + lane;
  float h = 0.f;
#pragma unroll
  for (int c = 0; c < NCHUNK; c++) {
    const float a = aprod_buf[base + c * 256];
    const float o = hout_buf[base + c * 256];
    hout_buf[base + c * 256] = h;
    h = a * h + o;
  }
}

// pass2: re-run chunk from h_in; y = (scan_y + xc*Dskip) * silu(z) -> bf16
__global__ __launch_bounds__(256) void scan_pass2(
    const float* __restrict__ dt, const float* __restrict__ xc,
    const float* __restrict__ dbc, const float* __restrict__ A_log,
    const float* __restrict__ Dskip, const float* __restrict__ z,
    const float* __restrict__ hin_buf, unsigned short* __restrict__ y16) {
  const int b  = blockIdx.x >> 11;
  const int dg = (blockIdx.x >> 4) & 127;
  const int c  = blockIdx.x & 15;
  const int d0 = dg * 16;
  const int tid = threadIdx.x;
  const int g = tid >> 4, s = tid & 15;
  const float A = -expf(A_log[(d0 + g) * DST + s]);
  float h = hin_buf[((b * 128 + dg) * NCHUNK + c) * 256 + tid];
  __shared__ float sdt[64][16], su[64][16], sB[64][16], sC[64][16], sy[64][16];
  const int base_r = b * 2048 + c * CHLEN;
  for (int t0 = 0; t0 < CHLEN; t0 += 64) {
    __syncthreads();
#pragma unroll
    for (int i = 0; i < 4; i++) {
      const int flat = tid + i * 256;
      const int tt = flat >> 4, dd = flat & 15;
      const size_t r = base_r + t0 + tt;
      sdt[tt][dd] = dt[r * 4096 + d0 + dd];
      su[tt][dd]  = xc[r * 2048 + d0 + dd];
      sB[tt][dd]  = dbc[r * 96 + DTR + dd];
      sC[tt][dd]  = dbc[r * 96 + DTR + DST + dd];
    }
    __syncthreads();
#pragma unroll 4
    for (int tt = 0; tt < 64; tt++) {
      const float dtv = sdt[tt][g];
      const float a = __expf(dtv * A);
      h = a * h + (dtv * su[tt][g]) * sB[tt][s];
      float p = h * sC[tt][s];
      p += __shfl_xor(p, 8);
      p += __shfl_xor(p, 4);
      p += __shfl_xor(p, 2);
      p += __shfl_xor(p, 1);
      if (s == 0) sy[tt][g] = p;
    }
    __syncthreads();
#pragma unroll
    for (int i = 0; i < 4; i++) {
      const int flat = tid + i * 256;
      const int tt = flat >> 4, dd = flat & 15;
      const size_t r = base_r + t0 + tt;
      float yv = sy[tt][dd] + su[tt][dd] * Dskip[d0 + dd];
      const float zv = z[r * 4096 + d0 + dd];
      yv *= silu_f(zv);
      y16[r * 2048 + d0 + dd] = f2bf(yv);
    }
  }
}

// ---------------------------------------------------------------- launch
extern "C" void kernel_launch(void* const* d_in, const int* in_sizes, int n_in,
                              void* d_out, int out_size, void* d_ws, size_t ws_size,
                              hipStream_t stream) {
  const float* x         = (const float*)d_in[0];
  const float* ln_w      = (const float*)d_in[1];
  const float* ln_b      = (const float*)d_in[2];
  const float* in_proj_w = (const float*)d_in[3];
  const float* conv_w    = (const float*)d_in[4];
  const float* conv_b    = (const float*)d_in[5];
  const float* x_proj_w  = (const float*)d_in[6];
  const float* dt_proj_w = (const float*)d_in[7];
  const float* dt_proj_b = (const float*)d_in[8];
  const float* A_log     = (const float*)d_in[9];
  const float* D_skip    = (const float*)d_in[10];
  const float* out_proj_w= (const float*)d_in[11];
  float* out = (float*)d_out;
  float* ws  = (float*)d_ws;

  unsigned short* xnb  = (unsigned short*)ws;          // 4M bf16    [0, 2M floats)
  float* aprod = ws + (2u << 20);                      // [2M, 3M)
  float* hout  = ws + (3u << 20);                      // [3M, 4M)
  float* xz    = ws + (4u << 20);                      // [4M, 20M)
  float* xc    = ws + (20u << 20);                     // [20M, 28M)
  float* dbc   = ws + (28u << 20);                     // [28M, +0.4M)
  unsigned short* wtin  = (unsigned short*)(ws + (29u << 20));  // 4096x1024 bf16
  unsigned short* wtout = (unsigned short*)(ws + (31u << 20));  // 1024x2048 bf16
  unsigned short* yb16  = (unsigned short*)(ws + (32u << 20));  // 4096x2048 bf16
  float* dtb = xz;          // dt overwrites xi in place (ld 4096)
  float* zp  = xz + DI;     // z (ld 4096)

  // 0. weight transpose+convert: Wt[N][K] bf16
  transpose_bf16<<<dim3(4096 / 32, 1024 / 32), 256, 0, stream>>>(in_proj_w, wtin, DM, 4096);
  transpose_bf16<<<dim3(1024 / 32, 2048 / 32), 256, 0, stream>>>(out_proj_w, wtout, DI, DM);
  // 1. LayerNorm -> bf16
  ln_kernel<<<NROWS, 256, 0, stream>>>(x, ln_w, ln_b, xnb);
  // 2. in_proj: xz = xn @ W  (M=4096,N=4096,K=1024) MFMA
  gemm_mfma<0><<<dim3(32, 32), 256, 0, stream>>>(xnb, wtin, xz, NROWS, 4096, DM, nullptr);
  // 3. depthwise conv + silu -> xc
  conv_silu_kernel<<<8192, 256, 0, stream>>>(xz, conv_w, conv_b, xc);
  // 4. x_proj: dbc = xc @ x_proj_w  (N=96, K=2048) fp32
  gemm_kernel<0><<<dim3(2, 64), 256, 0, stream>>>(xc, x_proj_w, dbc,
      NROWS, 96, DI, DI, 96, 96, nullptr);
  // 5. dt_proj + softplus (K=64) fp32
  gemm_kernel<1><<<dim3(32, 64), 256, 0, stream>>>(dbc, dt_proj_w, dtb,
      NROWS, DI, DTR, 96, DI, 4096, dt_proj_b);
  // 6. chunked selective scan -> y bf16
  scan_pass1<<<4096, 256, 0, stream>>>(dtb, xc, dbc, A_log, aprod, hout);
  scan_fixup<<<256, 256, 0, stream>>>(aprod, hout);
  scan_pass2<<<4096, 256, 0, stream>>>(dtb, xc, dbc, A_log, D_skip, zp, hout, yb16);
  // 7. out_proj + residual: out = x + y @ out_proj_w  (N=1024, K=2048) MFMA
  gemm_mfma<2><<<dim3(8, 32), 256, 0, stream>>>(yb16, wtout, out, NROWS, DM, DI, x);
}

// Round 7
// 472.034 us; speedup vs baseline: 3.5597x; 1.2595x over previous
//
#include <hip/hip_runtime.h>
#include <math.h>

#define NROWS 4096   // BATCH*SEQ
#define DM    1024   // D_MODEL
#define DI    2048   // D_INNER
#define DTR   64     // DT_RANK
#define DST   16     // D_STATE
#define NCHUNK 16
#define CHLEN  128   // 2048 / NCHUNK
#define XKS   8      // x_proj K-splits
#define XKL   256    // 2048 / XKS

typedef __attribute__((ext_vector_type(8))) short bf16x8;
typedef __attribute__((ext_vector_type(4))) float f32x4;

__device__ __forceinline__ unsigned short f2bf(float f) {
  unsigned u = __float_as_uint(f);
  u = (u + 0x7fffu + ((u >> 16) & 1u)) >> 16;   // RNE
  return (unsigned short)u;
}
__device__ __forceinline__ float softplus_f(float v) {
  return fmaxf(v, 0.f) + log1pf(__expf(-fabsf(v)));
}
__device__ __forceinline__ float silu_f(float v) {
  return v * (1.f / (1.f + __expf(-v)));
}
__device__ __forceinline__ void gload_lds16(const void* g, void* l) {
  __builtin_amdgcn_global_load_lds(
      (const __attribute__((address_space(1))) void*)g,
      (__attribute__((address_space(3))) void*)l, 16, 0, 0);
}

// ---------------------------------------------------------------- LayerNorm -> bf16
__global__ __launch_bounds__(256) void ln_kernel(const float* __restrict__ x,
                                                 const float* __restrict__ w,
                                                 const float* __restrict__ b,
                                                 unsigned short* __restrict__ xnb) {
  const int row = blockIdx.x;
  const int tid = threadIdx.x;
  const float4 v = ((const float4*)(x + (size_t)row * DM))[tid];
  float s  = v.x + v.y + v.z + v.w;
  float ss = v.x * v.x + v.y * v.y + v.z * v.z + v.w * v.w;
  for (int off = 32; off > 0; off >>= 1) {
    s  += __shfl_down(s, off);
    ss += __shfl_down(ss, off);
  }
  __shared__ float red[4][2];
  if ((tid & 63) == 0) { red[tid >> 6][0] = s; red[tid >> 6][1] = ss; }
  __syncthreads();
  const float fs  = red[0][0] + red[1][0] + red[2][0] + red[3][0];
  const float fss = red[0][1] + red[1][1] + red[2][1] + red[3][1];
  const float mu  = fs * (1.f / DM);
  const float var = fss * (1.f / DM) - mu * mu;
  const float rs  = rsqrtf(var + 1e-5f);
  const float4 wv = ((const float4*)w)[tid];
  const float4 bv = ((const float4*)b)[tid];
  ushort4 o;
  o.x = f2bf((v.x - mu) * rs * wv.x + bv.x);
  o.y = f2bf((v.y - mu) * rs * wv.y + bv.y);
  o.z = f2bf((v.z - mu) * rs * wv.z + bv.z);
  o.w = f2bf((v.w - mu) * rs * wv.w + bv.w);
  ((ushort4*)(xnb + (size_t)row * DM))[tid] = o;
}

// ---------------------------------------------------------------- W[K][N] f32 -> Wt[N][K] bf16
__global__ __launch_bounds__(256) void transpose_bf16(const float* __restrict__ W,
                                                      unsigned short* __restrict__ Wt,
                                                      int K, int N) {
  __shared__ float t[32][33];
  const int n0 = blockIdx.x * 32, k0 = blockIdx.y * 32;
  const int tx = threadIdx.x & 31, ty = threadIdx.x >> 5;  // ty 0..7
#pragma unroll
  for (int i = 0; i < 4; i++)
    t[ty + i * 8][tx] = W[(size_t)(k0 + ty + i * 8) * N + n0 + tx];
  __syncthreads();
#pragma unroll
  for (int i = 0; i < 4; i++)
    Wt[(size_t)(n0 + ty + i * 8) * K + k0 + tx] = f2bf(t[tx][ty + i * 8]);
}

// ---------------------------------------------------------------- bf16 MFMA GEMM
// C[M,N] = A[M,K](bf16) @ Bt[N,K](bf16)^T; 128x128 tile, BK=32, 4 waves 2x2.
template <int EPI>   // 0 none, 2 acc + resid
__global__ __launch_bounds__(256) void gemm_mfma(
    const unsigned short* __restrict__ A, const unsigned short* __restrict__ Bt,
    float* __restrict__ C, int M, int N, int K, const float* __restrict__ resid) {
  __shared__ unsigned short Asl[128 * 32];
  __shared__ unsigned short Bsl[128 * 32];
  const int tid  = threadIdx.x;
  const int wave = tid >> 6, lane = tid & 63;
  const int wr = wave >> 1, wc = wave & 1;
  const int m0 = blockIdx.y * 128, n0 = blockIdx.x * 128;
  const int srow = lane >> 2;
  const int skoff = (lane & 3) * 8;
  f32x4 acc[4][4] = {};
  for (int k0 = 0; k0 < K; k0 += 32) {
    __syncthreads();
#pragma unroll
    for (int i = 0; i < 2; i++) {
      const int c = wave * 2 + i;
      gload_lds16(A  + (size_t)(m0 + c * 16 + srow) * K + k0 + skoff, &Asl[c * 512]);
      gload_lds16(Bt + (size_t)(n0 + c * 16 + srow) * K + k0 + skoff, &Bsl[c * 512]);
    }
    __syncthreads();
    bf16x8 af[4], bfr[4];
#pragma unroll
    for (int m = 0; m < 4; m++)
      af[m] = *(const bf16x8*)&Asl[(wr * 64 + m * 16 + (lane & 15)) * 32 + (lane >> 4) * 8];
#pragma unroll
    for (int n = 0; n < 4; n++)
      bfr[n] = *(const bf16x8*)&Bsl[(wc * 64 + n * 16 + (lane & 15)) * 32 + (lane >> 4) * 8];
#pragma unroll
    for (int m = 0; m < 4; m++)
#pragma unroll
      for (int n = 0; n < 4; n++)
        acc[m][n] = __builtin_amdgcn_mfma_f32_16x16x32_bf16(af[m], bfr[n], acc[m][n], 0, 0, 0);
  }
#pragma unroll
  for (int m = 0; m < 4; m++) {
#pragma unroll
    for (int n = 0; n < 4; n++) {
      const int col = n0 + wc * 64 + n * 16 + (lane & 15);
#pragma unroll
      for (int r = 0; r < 4; r++) {
        const int row = m0 + wr * 64 + m * 16 + (lane >> 4) * 4 + r;
        float v = acc[m][n][r];
        if (EPI == 2) v += resid[(size_t)row * N + col];
        C[(size_t)row * N + col] = v;
      }
    }
  }
}

// ---------------------------------------------------------------- x_proj split-K
// part[ks][4096][96] += xc[64 rows][K slice] @ B[K slice][96]
__global__ __launch_bounds__(256) void xproj_splitk(
    const float* __restrict__ A,   // xc [4096][2048]
    const float* __restrict__ B,   // x_proj_w [2048][96]
    float* __restrict__ part) {
  __shared__ float AsT[32][68];    // k-major; 68: 16B-aligned rows, conflict-free
  __shared__ float Bs[32][96];
  const int ks = blockIdx.x;       // 0..7
  const int r0 = blockIdx.y * 64;
  const int tid = threadIdx.x;
  const int rg = tid >> 4;         // 0..15 -> rows rg*4..+3
  const int cg = tid & 15;         // cols cg*6..+5
  const int arow = tid >> 2;       // staging: 0..63
  const int ac   = (tid & 3) * 2;  // float4-chunks {ac, ac+1} of 8
  const int bk   = tid >> 3;       // 0..31
  const int bc   = tid & 7;        // col chunks {bc, bc+8, bc+16}
  float acc[4][6] = {};
  const int k0base = ks * XKL;
  for (int kt = 0; kt < XKL; kt += 32) {
    const int k0 = k0base + kt;
    const float4 a0 = *(const float4*)&A[(size_t)(r0 + arow) * DI + k0 + ac * 4];
    const float4 a1 = *(const float4*)&A[(size_t)(r0 + arow) * DI + k0 + (ac + 1) * 4];
    const float4 b0 = *(const float4*)&B[(size_t)(k0 + bk) * 96 + bc * 4];
    const float4 b1 = *(const float4*)&B[(size_t)(k0 + bk) * 96 + (bc + 8) * 4];
    const float4 b2 = *(const float4*)&B[(size_t)(k0 + bk) * 96 + (bc + 16) * 4];
    __syncthreads();
#pragma unroll
    for (int j = 0; j < 4; j++) AsT[ac * 4 + j][arow] = (&a0.x)[j];
#pragma unroll
    for (int j = 0; j < 4; j++) AsT[(ac + 1) * 4 + j][arow] = (&a1.x)[j];
    *(float4*)&Bs[bk][bc * 4] = b0;
    *(float4*)&Bs[bk][(bc + 8) * 4] = b1;
    *(float4*)&Bs[bk][(bc + 16) * 4] = b2;
    __syncthreads();
#pragma unroll
    for (int k = 0; k < 32; k++) {
      const float4 av = *(const float4*)&AsT[k][rg * 4];
      const float2 bv0 = *(const float2*)&Bs[k][cg * 6];
      const float2 bv1 = *(const float2*)&Bs[k][cg * 6 + 2];
      const float2 bv2 = *(const float2*)&Bs[k][cg * 6 + 4];
#pragma unroll
      for (int i = 0; i < 4; i++) {
        const float a = (&av.x)[i];
        acc[i][0] += a * bv0.x; acc[i][1] += a * bv0.y;
        acc[i][2] += a * bv1.x; acc[i][3] += a * bv1.y;
        acc[i][4] += a * bv2.x; acc[i][5] += a * bv2.y;
      }
    }
  }
#pragma unroll
  for (int i = 0; i < 4; i++) {
    const int row = r0 + rg * 4 + i;
    float* p = &part[((size_t)ks * NROWS + row) * 96 + cg * 6];
#pragma unroll
    for (int j = 0; j < 3; j++)
      *(float2*)&p[j * 2] = make_float2(acc[i][j * 2], acc[i][j * 2 + 1]);
  }
}

__global__ __launch_bounds__(256) void xproj_reduce(const float* __restrict__ part,
                                                    float* __restrict__ dbc) {
  const int i = blockIdx.x * 256 + threadIdx.x;  // < 4096*96
  float s = 0.f;
#pragma unroll
  for (int ks = 0; ks < XKS; ks++) s += part[(size_t)ks * (NROWS * 96) + i];
  dbc[i] = s;
}

// ---------------------------------------------------------------- generic fp32 GEMM (dt_proj)
template <int EPI>  // 1: softplus(acc + bias[n])
__global__ __launch_bounds__(256) void gemm_kernel(
    const float* __restrict__ A, const float* __restrict__ B,
    float* __restrict__ C, int M, int N, int K, int lda, int ldb, int ldc,
    const float* __restrict__ bias) {
  __shared__ float As[64][20];
  __shared__ float Bs[16][64];
  const int tid = threadIdx.x;
  const int m0 = blockIdx.y * 64, n0 = blockIdx.x * 64;
  const int tx = tid & 15, ty = tid >> 4;
  const int am = tid >> 2, ak4 = (tid & 3) << 2;
  const int bk = tid >> 4, bn4 = (tid & 15) << 2;
  const bool bin = (n0 + bn4) < N;
  float acc[4][4] = {};
  for (int k0 = 0; k0 < K; k0 += 16) {
    const float4 av = *(const float4*)&A[(size_t)(m0 + am) * lda + k0 + ak4];
    float4 bv = make_float4(0.f, 0.f, 0.f, 0.f);
    if (bin) bv = *(const float4*)&B[(size_t)(k0 + bk) * ldb + n0 + bn4];
    __syncthreads();
    *(float4*)&As[am][ak4] = av;
    *(float4*)&Bs[bk][bn4] = bv;
    __syncthreads();
#pragma unroll
    for (int k4 = 0; k4 < 4; k4++) {
      float4 aa[4], bb[4];
#pragma unroll
      for (int i = 0; i < 4; i++) aa[i] = *(const float4*)&As[ty * 4 + i][k4 * 4];
#pragma unroll
      for (int kk = 0; kk < 4; kk++) bb[kk] = *(const float4*)&Bs[k4 * 4 + kk][tx * 4];
#pragma unroll
      for (int kk = 0; kk < 4; kk++) {
#pragma unroll
        for (int i = 0; i < 4; i++) {
          const float a = (&aa[i].x)[kk];
          acc[i][0] += a * bb[kk].x;
          acc[i][1] += a * bb[kk].y;
          acc[i][2] += a * bb[kk].z;
          acc[i][3] += a * bb[kk].w;
        }
      }
    }
  }
#pragma unroll
  for (int i = 0; i < 4; i++) {
    const int row = m0 + ty * 4 + i;
    const int col = n0 + tx * 4;
    if (col < N) {
      float4 o = make_float4(acc[i][0], acc[i][1], acc[i][2], acc[i][3]);
      if (EPI == 1) {
        const float4 bi = *(const float4*)&bias[col];
        o.x = softplus_f(o.x + bi.x);
        o.y = softplus_f(o.y + bi.y);
        o.z = softplus_f(o.z + bi.z);
        o.w = softplus_f(o.w + bi.w);
      }
      *(float4*)&C[(size_t)row * ldc + col] = o;
    }
  }
}

// ---------------------------------------------------------------- depthwise causal conv + SiLU
__global__ __launch_bounds__(256) void conv_silu_kernel(const float* __restrict__ xz,
                                                        const float* __restrict__ cw,
                                                        const float* __restrict__ cb,
                                                        float* __restrict__ xc) {
  const int idx = blockIdx.x * 256 + threadIdx.x;
  const int d4 = (idx & 511) << 2;
  const int r = idx >> 9;
  const int t = r & 2047;
  const float4 w0 = *(const float4*)&cw[(d4 + 0) * 4];
  const float4 w1 = *(const float4*)&cw[(d4 + 1) * 4];
  const float4 w2 = *(const float4*)&cw[(d4 + 2) * 4];
  const float4 w3 = *(const float4*)&cw[(d4 + 3) * 4];
  float4 acc = *(const float4*)&cb[d4];
#pragma unroll
  for (int j = 0; j < 4; j++) {
    const int tj = t - 3 + j;
    if (tj >= 0) {
      const float4 xv = *(const float4*)&xz[(size_t)(r - 3 + j) * 4096 + d4];
      acc.x += xv.x * (&w0.x)[j];
      acc.y += xv.y * (&w1.x)[j];
      acc.z += xv.z * (&w2.x)[j];
      acc.w += xv.w * (&w3.x)[j];
    }
  }
  acc.x = silu_f(acc.x); acc.y = silu_f(acc.y);
  acc.z = silu_f(acc.z); acc.w = silu_f(acc.w);
  *(float4*)&xc[(size_t)r * DI + d4] = acc;
}

// ---------------------------------------------------------------- chunked selective scan
__global__ __launch_bounds__(256) void scan_pass1(
    const float* __restrict__ dt, const float* __restrict__ xc,
    const float* __restrict__ dbc, const float* __restrict__ A_log,
    float* __restrict__ aprod_buf, float* __restrict__ hout_buf) {
  const int b  = blockIdx.x >> 11;
  const int dg = (blockIdx.x >> 4) & 127;
  const int c  = blockIdx.x & 15;
  const int d0 = dg * 16;
  const int tid = threadIdx.x;
  const int g = tid >> 4, s = tid & 15;
  const float A = -expf(A_log[(d0 + g) * DST + s]);
  float h = 0.f, ap = 1.f;
  __shared__ float sdt[64][16], su[64][16], sB[64][16];
  const int base_r = b * 2048 + c * CHLEN;
  for (int t0 = 0; t0 < CHLEN; t0 += 64) {
    __syncthreads();
#pragma unroll
    for (int i = 0; i < 4; i++) {
      const int flat = tid + i * 256;
      const int tt = flat >> 4, dd = flat & 15;
      const size_t r = base_r + t0 + tt;
      sdt[tt][dd] = dt[r * 4096 + d0 + dd];
      su[tt][dd]  = xc[r * 2048 + d0 + dd];
      sB[tt][dd]  = dbc[r * 96 + DTR + dd];
    }
    __syncthreads();
#pragma unroll 8
    for (int tt = 0; tt < 64; tt++) {
      const float dtv = sdt[tt][g];
      const float a = __expf(dtv * A);
      h = a * h + (dtv * su[tt][g]) * sB[tt][s];
      ap *= a;
    }
  }
  const int idx = ((b * 128 + dg) * NCHUNK + c) * 256 + tid;
  aprod_buf[idx] = ap;
  hout_buf[idx]  = h;
}

__global__ __launch_bounds__(256) void scan_fixup(const float* __restrict__ aprod_buf,
                                                  float* __restrict__ hout_buf) {
  const int t = blockIdx.x * 256 + threadIdx.x;
  const int seq = t >> 8;
  const int lane = t & 255;
  const int base = seq * NCHUNK * 256 + lane;
  float h = 0.f;
#pragma unroll
  for (int c = 0; c < NCHUNK; c++) {
    const float a = aprod_buf[base + c * 256];
    const float o = hout_buf[base + c * 256];
    hout_buf[base + c * 256] = h;
    h = a * h + o;
  }
}

__global__ __launch_bounds__(256) void scan_pass2(
    const float* __restrict__ dt, const float* __restrict__ xc,
    const float* __restrict__ dbc, const float* __restrict__ A_log,
    const float* __restrict__ Dskip, const float* __restrict__ z,
    const float* __restrict__ hin_buf, unsigned short* __restrict__ y16) {
  const int b  = blockIdx.x >> 11;
  const int dg = (blockIdx.x >> 4) & 127;
  const int c  = blockIdx.x & 15;
  const int d0 = dg * 16;
  const int tid = threadIdx.x;
  const int g = tid >> 4, s = tid & 15;
  const float A = -expf(A_log[(d0 + g) * DST + s]);
  float h = hin_buf[((b * 128 + dg) * NCHUNK + c) * 256 + tid];
  __shared__ float sdt[64][16], su[64][16], sB[64][16], sC[64][16], sy[64][16];
  const int base_r = b * 2048 + c * CHLEN;
  for (int t0 = 0; t0 < CHLEN; t0 += 64) {
    __syncthreads();
#pragma unroll
    for (int i = 0; i < 4; i++) {
      const int flat = tid + i * 256;
      const int tt = flat >> 4, dd = flat & 15;
      const size_t r = base_r + t0 + tt;
      sdt[tt][dd] = dt[r * 4096 + d0 + dd];
      su[tt][dd]  = xc[r * 2048 + d0 + dd];
      sB[tt][dd]  = dbc[r * 96 + DTR + dd];
      sC[tt][dd]  = dbc[r * 96 + DTR + DST + dd];
    }
    __syncthreads();
#pragma unroll 4
    for (int tt = 0; tt < 64; tt++) {
      const float dtv = sdt[tt][g];
      const float a = __expf(dtv * A);
      h = a * h + (dtv * su[tt][g]) * sB[tt][s];
      float p = h * sC[tt][s];
      p += __shfl_xor(p, 8);
      p += __shfl_xor(p, 4);
      p += __shfl_xor(p, 2);
      p += __shfl_xor(p, 1);
      if (s == 0) sy[tt][g] = p;
    }
    __syncthreads();
#pragma unroll
    for (int i = 0; i < 4; i++) {
      const int flat = tid + i * 256;
      const int tt = flat >> 4, dd = flat & 15;
      const size_t r = base_r + t0 + tt;
      float yv = sy[tt][dd] + su[tt][dd] * Dskip[d0 + dd];
      const float zv = z[r * 4096 + d0 + dd];
      yv *= silu_f(zv);
      y16[r * 2048 + d0 + dd] = f2bf(yv);
    }
  }
}

// ---------------------------------------------------------------- launch
extern "C" void kernel_launch(void* const* d_in, const int* in_sizes, int n_in,
                              void* d_out, int out_size, void* d_ws, size_t ws_size,
                              hipStream_t stream) {
  const float* x         = (const float*)d_in[0];
  const float* ln_w      = (const float*)d_in[1];
  const float* ln_b      = (const float*)d_in[2];
  const float* in_proj_w = (const float*)d_in[3];
  const float* conv_w    = (const float*)d_in[4];
  const float* conv_b    = (const float*)d_in[5];
  const float* x_proj_w  = (const float*)d_in[6];
  const float* dt_proj_w = (const float*)d_in[7];
  const float* dt_proj_b = (const float*)d_in[8];
  const float* A_log     = (const float*)d_in[9];
  const float* D_skip    = (const float*)d_in[10];
  const float* out_proj_w= (const float*)d_in[11];
  float* out = (float*)d_out;
  float* ws  = (float*)d_ws;

  unsigned short* xnb  = (unsigned short*)ws;          // [0, 2M floats) live steps 1-2
  float* part  = ws;                                   // [0, 3M) x_proj partials (step 4; xnb dead)
  float* aprod = ws + (2u << 20);                      // [2M, 3M) written step 6 (part dead)
  float* hout  = ws + (3u << 20);                      // [3M, 4M)
  float* xz    = ws + (4u << 20);                      // [4M, 20M)
  float* xc    = ws + (20u << 20);                     // [20M, 28M)
  float* dbc   = ws + (28u << 20);                     // [28M, +0.375M)
  unsigned short* wtin  = (unsigned short*)(ws + (29u << 20));  // 4096x1024 bf16
  unsigned short* wtout = (unsigned short*)(ws + (31u << 20));  // 1024x2048 bf16
  unsigned short* yb16  = (unsigned short*)(ws + (32u << 20));  // 4096x2048 bf16
  float* dtb = xz;          // dt overwrites xi in place (ld 4096)
  float* zp  = xz + DI;     // z (ld 4096)

  // 0. weight transpose+convert: Wt[N][K] bf16
  transpose_bf16<<<dim3(4096 / 32, 1024 / 32), 256, 0, stream>>>(in_proj_w, wtin, DM, 4096);
  transpose_bf16<<<dim3(1024 / 32, 2048 / 32), 256, 0, stream>>>(out_proj_w, wtout, DI, DM);
  // 1. LayerNorm -> bf16
  ln_kernel<<<NROWS, 256, 0, stream>>>(x, ln_w, ln_b, xnb);
  // 2. in_proj: xz = xn @ W  (M=4096,N=4096,K=1024) MFMA
  gemm_mfma<0><<<dim3(32, 32), 256, 0, stream>>>(xnb, wtin, xz, NROWS, 4096, DM, nullptr);
  // 3. depthwise conv + silu -> xc
  conv_silu_kernel<<<8192, 256, 0, stream>>>(xz, conv_w, conv_b, xc);
  // 4. x_proj split-K: part = xc @ x_proj_w, then reduce -> dbc
  xproj_splitk<<<dim3(XKS, 64), 256, 0, stream>>>(xc, x_proj_w, part);
  xproj_reduce<<<(NROWS * 96) / 256, 256, 0, stream>>>(part, dbc);
  // 5. dt_proj + softplus (K=64) fp32
  gemm_kernel<1><<<dim3(32, 64), 256, 0, stream>>>(dbc, dt_proj_w, dtb,
      NROWS, DI, DTR, 96, DI, 4096, dt_proj_b);
  // 6. chunked selective scan -> y bf16
  scan_pass1<<<4096, 256, 0, stream>>>(dtb, xc, dbc, A_log, aprod, hout);
  scan_fixup<<<256, 256, 0, stream>>>(aprod, hout);
  scan_pass2<<<4096, 256, 0, stream>>>(dtb, xc, dbc, A_log, D_skip, zp, hout, yb16);
  // 7. out_proj + residual: out = x + y @ out_proj_w  (N=1024, K=2048) MFMA
  gemm_mfma<2><<<dim3(8, 32), 256, 0, stream>>>(yb16, wtout, out, NROWS, DM, DI, x);
}

// Round 10
// 408.066 us; speedup vs baseline: 4.1177x; 1.1568x over previous
//
#include <hip/hip_runtime.h>
#include <math.h>

#define NROWS 4096   // BATCH*SEQ
#define DM    1024   // D_MODEL
#define DI    2048   // D_INNER
#define DTR   64     // DT_RANK
#define DST   16     // D_STATE
#define NCHUNK 32
#define CHLEN  64    // 2048 / NCHUNK
#define XKS   8      // x_proj K-splits
#define XKL   256    // 2048 / XKS

typedef __attribute__((ext_vector_type(8))) short bf16x8;
typedef __attribute__((ext_vector_type(4))) float f32x4;

__device__ __forceinline__ unsigned short f2bf(float f) {
  unsigned u = __float_as_uint(f);
  u = (u + 0x7fffu + ((u >> 16) & 1u)) >> 16;   // RNE
  return (unsigned short)u;
}
__device__ __forceinline__ float softplus_f(float v) {
  return fmaxf(v, 0.f) + log1pf(__expf(-fabsf(v)));
}
__device__ __forceinline__ float silu_f(float v) {
  return v * (1.f / (1.f + __expf(-v)));
}
__device__ __forceinline__ void gload_lds16(const void* g, void* l) {
  __builtin_amdgcn_global_load_lds(
      (const __attribute__((address_space(1))) void*)g,
      (__attribute__((address_space(3))) void*)l, 16, 0, 0);
}

// ---------------------------------------------------------------- LayerNorm -> bf16
__global__ __launch_bounds__(256) void ln_kernel(const float* __restrict__ x,
                                                 const float* __restrict__ w,
                                                 const float* __restrict__ b,
                                                 unsigned short* __restrict__ xnb) {
  const int row = blockIdx.x;
  const int tid = threadIdx.x;
  const float4 v = ((const float4*)(x + (size_t)row * DM))[tid];
  float s  = v.x + v.y + v.z + v.w;
  float ss = v.x * v.x + v.y * v.y + v.z * v.z + v.w * v.w;
  for (int off = 32; off > 0; off >>= 1) {
    s  += __shfl_down(s, off);
    ss += __shfl_down(ss, off);
  }
  __shared__ float red[4][2];
  if ((tid & 63) == 0) { red[tid >> 6][0] = s; red[tid >> 6][1] = ss; }
  __syncthreads();
  const float fs  = red[0][0] + red[1][0] + red[2][0] + red[3][0];
  const float fss = red[0][1] + red[1][1] + red[2][1] + red[3][1];
  const float mu  = fs * (1.f / DM);
  const float var = fss * (1.f / DM) - mu * mu;
  const float rs  = rsqrtf(var + 1e-5f);
  const float4 wv = ((const float4*)w)[tid];
  const float4 bv = ((const float4*)b)[tid];
  ushort4 o;
  o.x = f2bf((v.x - mu) * rs * wv.x + bv.x);
  o.y = f2bf((v.y - mu) * rs * wv.y + bv.y);
  o.z = f2bf((v.z - mu) * rs * wv.z + bv.z);
  o.w = f2bf((v.w - mu) * rs * wv.w + bv.w);
  ((ushort4*)(xnb + (size_t)row * DM))[tid] = o;
}

// ---------------------------------------------------------------- W[K][N] f32 -> Wt[N][K] bf16
__global__ __launch_bounds__(256) void transpose_bf16(const float* __restrict__ W,
                                                      unsigned short* __restrict__ Wt,
                                                      int K, int N) {
  __shared__ float t[32][33];
  const int n0 = blockIdx.x * 32, k0 = blockIdx.y * 32;
  const int tx = threadIdx.x & 31, ty = threadIdx.x >> 5;  // ty 0..7
#pragma unroll
  for (int i = 0; i < 4; i++)
    t[ty + i * 8][tx] = W[(size_t)(k0 + ty + i * 8) * N + n0 + tx];
  __syncthreads();
#pragma unroll
  for (int i = 0; i < 4; i++)
    Wt[(size_t)(n0 + ty + i * 8) * K + k0 + tx] = f2bf(t[tx][ty + i * 8]);
}

// ---------------------------------------------------------------- bf16 MFMA GEMM
// C[M,N] = A[M,K](bf16) @ Bt[N,K](bf16)^T; 128x128 tile, BK=32, 4 waves 2x2.
template <int EPI>   // 0 none, 2 acc + resid
__global__ __launch_bounds__(256) void gemm_mfma(
    const unsigned short* __restrict__ A, const unsigned short* __restrict__ Bt,
    float* __restrict__ C, int M, int N, int K, const float* __restrict__ resid) {
  __shared__ unsigned short Asl[128 * 32];
  __shared__ unsigned short Bsl[128 * 32];
  const int tid  = threadIdx.x;
  const int wave = tid >> 6, lane = tid & 63;
  const int wr = wave >> 1, wc = wave & 1;
  const int m0 = blockIdx.y * 128, n0 = blockIdx.x * 128;
  const int srow = lane >> 2;
  const int skoff = (lane & 3) * 8;
  f32x4 acc[4][4] = {};
  for (int k0 = 0; k0 < K; k0 += 32) {
    __syncthreads();
#pragma unroll
    for (int i = 0; i < 2; i++) {
      const int c = wave * 2 + i;
      gload_lds16(A  + (size_t)(m0 + c * 16 + srow) * K + k0 + skoff, &Asl[c * 512]);
      gload_lds16(Bt + (size_t)(n0 + c * 16 + srow) * K + k0 + skoff, &Bsl[c * 512]);
    }
    __syncthreads();
    bf16x8 af[4], bfr[4];
#pragma unroll
    for (int m = 0; m < 4; m++)
      af[m] = *(const bf16x8*)&Asl[(wr * 64 + m * 16 + (lane & 15)) * 32 + (lane >> 4) * 8];
#pragma unroll
    for (int n = 0; n < 4; n++)
      bfr[n] = *(const bf16x8*)&Bsl[(wc * 64 + n * 16 + (lane & 15)) * 32 + (lane >> 4) * 8];
#pragma unroll
    for (int m = 0; m < 4; m++)
#pragma unroll
      for (int n = 0; n < 4; n++)
        acc[m][n] = __builtin_amdgcn_mfma_f32_16x16x32_bf16(af[m], bfr[n], acc[m][n], 0, 0, 0);
  }
#pragma unroll
  for (int m = 0; m < 4; m++) {
#pragma unroll
    for (int n = 0; n < 4; n++) {
      const int col = n0 + wc * 64 + n * 16 + (lane & 15);
#pragma unroll
      for (int r = 0; r < 4; r++) {
        const int row = m0 + wr * 64 + m * 16 + (lane >> 4) * 4 + r;
        float v = acc[m][n][r];
        if (EPI == 2) v += resid[(size_t)row * N + col];
        C[(size_t)row * N + col] = v;
      }
    }
  }
}

// ---------------------------------------------------------------- x_proj split-K
__global__ __launch_bounds__(256) void xproj_splitk(
    const float* __restrict__ A,   // xc [4096][2048]
    const float* __restrict__ B,   // x_proj_w [2048][96]
    float* __restrict__ part) {
  __shared__ float AsT[32][68];
  __shared__ float Bs[32][96];
  const int ks = blockIdx.x;       // 0..7
  const int r0 = blockIdx.y * 64;
  const int tid = threadIdx.x;
  const int rg = tid >> 4;
  const int cg = tid & 15;
  const int arow = tid >> 2;
  const int ac   = (tid & 3) * 2;
  const int bk   = tid >> 3;
  const int bc   = tid & 7;
  float acc[4][6] = {};
  const int k0base = ks * XKL;
  for (int kt = 0; kt < XKL; kt += 32) {
    const int k0 = k0base + kt;
    const float4 a0 = *(const float4*)&A[(size_t)(r0 + arow) * DI + k0 + ac * 4];
    const float4 a1 = *(const float4*)&A[(size_t)(r0 + arow) * DI + k0 + (ac + 1) * 4];
    const float4 b0 = *(const float4*)&B[(size_t)(k0 + bk) * 96 + bc * 4];
    const float4 b1 = *(const float4*)&B[(size_t)(k0 + bk) * 96 + (bc + 8) * 4];
    const float4 b2 = *(const float4*)&B[(size_t)(k0 + bk) * 96 + (bc + 16) * 4];
    __syncthreads();
#pragma unroll
    for (int j = 0; j < 4; j++) AsT[ac * 4 + j][arow] = (&a0.x)[j];
#pragma unroll
    for (int j = 0; j < 4; j++) AsT[(ac + 1) * 4 + j][arow] = (&a1.x)[j];
    *(float4*)&Bs[bk][bc * 4] = b0;
    *(float4*)&Bs[bk][(bc + 8) * 4] = b1;
    *(float4*)&Bs[bk][(bc + 16) * 4] = b2;
    __syncthreads();
#pragma unroll
    for (int k = 0; k < 32; k++) {
      const float4 av = *(const float4*)&AsT[k][rg * 4];
      const float2 bv0 = *(const float2*)&Bs[k][cg * 6];
      const float2 bv1 = *(const float2*)&Bs[k][cg * 6 + 2];
      const float2 bv2 = *(const float2*)&Bs[k][cg * 6 + 4];
#pragma unroll
      for (int i = 0; i < 4; i++) {
        const float a = (&av.x)[i];
        acc[i][0] += a * bv0.x; acc[i][1] += a * bv0.y;
        acc[i][2] += a * bv1.x; acc[i][3] += a * bv1.y;
        acc[i][4] += a * bv2.x; acc[i][5] += a * bv2.y;
      }
    }
  }
#pragma unroll
  for (int i = 0; i < 4; i++) {
    const int row = r0 + rg * 4 + i;
    float* p = &part[((size_t)ks * NROWS + row) * 96 + cg * 6];
#pragma unroll
    for (int j = 0; j < 3; j++)
      *(float2*)&p[j * 2] = make_float2(acc[i][j * 2], acc[i][j * 2 + 1]);
  }
}

__global__ __launch_bounds__(256) void xproj_reduce(const float* __restrict__ part,
                                                    float* __restrict__ dbc) {
  const int i = blockIdx.x * 256 + threadIdx.x;
  float s = 0.f;
#pragma unroll
  for (int ks = 0; ks < XKS; ks++) s += part[(size_t)ks * (NROWS * 96) + i];
  dbc[i] = s;
}

// ---------------------------------------------------------------- generic fp32 GEMM (dt_proj)
template <int EPI>  // 1: softplus(acc + bias[n])
__global__ __launch_bounds__(256) void gemm_kernel(
    const float* __restrict__ A, const float* __restrict__ B,
    float* __restrict__ C, int M, int N, int K, int lda, int ldb, int ldc,
    const float* __restrict__ bias) {
  __shared__ float As[64][20];
  __shared__ float Bs[16][64];
  const int tid = threadIdx.x;
  const int m0 = blockIdx.y * 64, n0 = blockIdx.x * 64;
  const int tx = tid & 15, ty = tid >> 4;
  const int am = tid >> 2, ak4 = (tid & 3) << 2;
  const int bk = tid >> 4, bn4 = (tid & 15) << 2;
  const bool bin = (n0 + bn4) < N;
  float acc[4][4] = {};
  for (int k0 = 0; k0 < K; k0 += 16) {
    const float4 av = *(const float4*)&A[(size_t)(m0 + am) * lda + k0 + ak4];
    float4 bv = make_float4(0.f, 0.f, 0.f, 0.f);
    if (bin) bv = *(const float4*)&B[(size_t)(k0 + bk) * ldb + n0 + bn4];
    __syncthreads();
    *(float4*)&As[am][ak4] = av;
    *(float4*)&Bs[bk][bn4] = bv;
    __syncthreads();
#pragma unroll
    for (int k4 = 0; k4 < 4; k4++) {
      float4 aa[4], bb[4];
#pragma unroll
      for (int i = 0; i < 4; i++) aa[i] = *(const float4*)&As[ty * 4 + i][k4 * 4];
#pragma unroll
      for (int kk = 0; kk < 4; kk++) bb[kk] = *(const float4*)&Bs[k4 * 4 + kk][tx * 4];
#pragma unroll
      for (int kk = 0; kk < 4; kk++) {
#pragma unroll
        for (int i = 0; i < 4; i++) {
          const float a = (&aa[i].x)[kk];
          acc[i][0] += a * bb[kk].x;
          acc[i][1] += a * bb[kk].y;
          acc[i][2] += a * bb[kk].z;
          acc[i][3] += a * bb[kk].w;
        }
      }
    }
  }
#pragma unroll
  for (int i = 0; i < 4; i++) {
    const int row = m0 + ty * 4 + i;
    const int col = n0 + tx * 4;
    if (col < N) {
      float4 o = make_float4(acc[i][0], acc[i][1], acc[i][2], acc[i][3]);
      if (EPI == 1) {
        const float4 bi = *(const float4*)&bias[col];
        o.x = softplus_f(o.x + bi.x);
        o.y = softplus_f(o.y + bi.y);
        o.z = softplus_f(o.z + bi.z);
        o.w = softplus_f(o.w + bi.w);
      }
      *(float4*)&C[(size_t)row * ldc + col] = o;
    }
  }
}

// ---------------------------------------------------------------- depthwise causal conv + SiLU
__global__ __launch_bounds__(256) void conv_silu_kernel(const float* __restrict__ xz,
                                                        const float* __restrict__ cw,
                                                        const float* __restrict__ cb,
                                                        float* __restrict__ xc) {
  const int idx = blockIdx.x * 256 + threadIdx.x;
  const int d4 = (idx & 511) << 2;
  const int r = idx >> 9;
  const int t = r & 2047;
  const float4 w0 = *(const float4*)&cw[(d4 + 0) * 4];
  const float4 w1 = *(const float4*)&cw[(d4 + 1) * 4];
  const float4 w2 = *(const float4*)&cw[(d4 + 2) * 4];
  const float4 w3 = *(const float4*)&cw[(d4 + 3) * 4];
  float4 acc = *(const float4*)&cb[d4];
#pragma unroll
  for (int j = 0; j < 4; j++) {
    const int tj = t - 3 + j;
    if (tj >= 0) {
      const float4 xv = *(const float4*)&xz[(size_t)(r - 3 + j) * 4096 + d4];
      acc.x += xv.x * (&w0.x)[j];
      acc.y += xv.y * (&w1.x)[j];
      acc.z += xv.z * (&w2.x)[j];
      acc.w += xv.w * (&w3.x)[j];
    }
  }
  acc.x = silu_f(acc.x); acc.y = silu_f(acc.y);
  acc.z = silu_f(acc.z); acc.w = silu_f(acc.w);
  *(float4*)&xc[(size_t)r * DI + d4] = acc;
}

// ---------------------------------------------------------------- chunked selective scan
// Register-state layout: thread owns channel d, 16 states in VGPRs. No LDS, no shuffles.
// grid: 2(b) x NCHUNK(c) x 8(dblk), 256 thr. Carries: [b][c][s][d] (coalesced both sides).
__global__ __launch_bounds__(256) void scan_pass1(
    const float* __restrict__ dt,    // ld 4096
    const float* __restrict__ xc,    // ld 2048
    const float* __restrict__ dbc,   // ld 96; B at +64 (uniform -> s_load)
    const float* __restrict__ A_log,
    float* __restrict__ aprod_buf, float* __restrict__ hout_buf) {
  const int bx = blockIdx.x;
  const int b = bx >> 8, c = (bx >> 3) & 31, dblk = bx & 7;
  const int d = dblk * 256 + threadIdx.x;
  float A[DST], h[DST], ap[DST];
#pragma unroll
  for (int s = 0; s < DST; s++) {
    A[s] = -expf(A_log[d * DST + s]);
    h[s] = 0.f; ap[s] = 1.f;
  }
  const int base_r = b * 2048 + c * CHLEN;
#pragma unroll 2
  for (int t = 0; t < CHLEN; t++) {
    const size_t r = base_r + t;
    const float dtv = dt[r * 4096 + d];
    const float uv  = xc[r * 2048 + d];
    const float du = dtv * uv;
    const float* bc = &dbc[r * 96 + DTR];
#pragma unroll
    for (int s = 0; s < DST; s++) {
      const float a = __expf(dtv * A[s]);
      h[s] = a * h[s] + du * bc[s];
      ap[s] *= a;
    }
  }
  const size_t base = ((size_t)(b * NCHUNK + c) * DST) * DI + d;
#pragma unroll
  for (int s = 0; s < DST; s++) {
    aprod_buf[base + (size_t)s * DI] = ap[s];
    hout_buf[base + (size_t)s * DI]  = h[s];
  }
}

// fixup: thread = (b,s,d); folds NCHUNK chunk carries -> per-chunk h_in (overwrites hout)
__global__ __launch_bounds__(256) void scan_fixup(const float* __restrict__ aprod_buf,
                                                  float* __restrict__ hout_buf) {
  const int gl = blockIdx.x * 256 + threadIdx.x;  // 65536
  const int d = gl & 2047, s = (gl >> 11) & 15, b = gl >> 15;
  const size_t base = ((size_t)(b * NCHUNK) * DST + s) * DI + d;
  const size_t stride = (size_t)DST * DI;
  float h = 0.f;
#pragma unroll
  for (int c = 0; c < NCHUNK; c++) {
    const float a = aprod_buf[base + c * stride];
    const float o = hout_buf[base + c * stride];
    hout_buf[base + c * stride] = h;
    h = a * h + o;
  }
}

// pass2: re-run chunk from h_in; y = (scan_y + xc*Dskip) * silu(z) -> bf16
__global__ __launch_bounds__(256) void scan_pass2(
    const float* __restrict__ dt, const float* __restrict__ xc,
    const float* __restrict__ dbc, const float* __restrict__ A_log,
    const float* __restrict__ Dskip, const float* __restrict__ z,
    const float* __restrict__ hin_buf, unsigned short* __restrict__ y16) {
  const int bx = blockIdx.x;
  const int b = bx >> 8, c = (bx >> 3) & 31, dblk = bx & 7;
  const int d = dblk * 256 + threadIdx.x;
  float A[DST], h[DST];
  const size_t base = ((size_t)(b * NCHUNK + c) * DST) * DI + d;
#pragma unroll
  for (int s = 0; s < DST; s++) {
    A[s] = -expf(A_log[d * DST + s]);
    h[s] = hin_buf[base + (size_t)s * DI];
  }
  const float dsk = Dskip[d];
  const int base_r = b * 2048 + c * CHLEN;
#pragma unroll 2
  for (int t = 0; t < CHLEN; t++) {
    const size_t r = base_r + t;
    const float dtv = dt[r * 4096 + d];
    const float uv  = xc[r * 2048 + d];
    const float zv  = z[r * 4096 + d];
    const float du = dtv * uv;
    const float* bc = &dbc[r * 96 + DTR];
    float y = 0.f;
#pragma unroll
    for (int s = 0; s < DST; s++) {
      const float a = __expf(dtv * A[s]);
      h[s] = a * h[s] + du * bc[s];
      y += h[s] * bc[DST + s];
    }
    y = (y + uv * dsk) * silu_f(zv);
    y16[r * 2048 + d] = f2bf(y);
  }
}

// ---------------------------------------------------------------- launch
extern "C" void kernel_launch(void* const* d_in, const int* in_sizes, int n_in,
                              void* d_out, int out_size, void* d_ws, size_t ws_size,
                              hipStream_t stream) {
  const float* x         = (const float*)d_in[0];
  const float* ln_w      = (const float*)d_in[1];
  const float* ln_b      = (const float*)d_in[2];
  const float* in_proj_w = (const float*)d_in[3];
  const float* conv_w    = (const float*)d_in[4];
  const float* conv_b    = (const float*)d_in[5];
  const float* x_proj_w  = (const float*)d_in[6];
  const float* dt_proj_w = (const float*)d_in[7];
  const float* dt_proj_b = (const float*)d_in[8];
  const float* A_log     = (const float*)d_in[9];
  const float* D_skip    = (const float*)d_in[10];
  const float* out_proj_w= (const float*)d_in[11];
  float* out = (float*)d_out;
  float* ws  = (float*)d_ws;

  unsigned short* xnb  = (unsigned short*)ws;          // [0, 2M floats) live steps 1-2
  float* part  = ws;                                   // [0, 3M) x_proj partials (step 4; xnb dead)
  float* aprod = ws;                                   // [0, 2M) carries (step 6; part dead)
  float* hout  = ws + (2u << 20);                      // [2M, 4M)
  float* xz    = ws + (4u << 20);                      // [4M, 20M)
  float* xc    = ws + (20u << 20);                     // [20M, 28M)
  float* dbc   = ws + (28u << 20);                     // [28M, +0.375M)
  unsigned short* wtin  = (unsigned short*)(ws + (29u << 20));  // 4096x1024 bf16
  unsigned short* wtout = (unsigned short*)(ws + (31u << 20));  // 1024x2048 bf16
  unsigned short* yb16  = (unsigned short*)(ws + (32u << 20));  // 4096x2048 bf16
  float* dtb = xz;          // dt overwrites xi in place (ld 4096)
  float* zp  = xz + DI;     // z (ld 4096)

  // 0. weight transpose+convert: Wt[N][K] bf16
  transpose_bf16<<<dim3(4096 / 32, 1024 / 32), 256, 0, stream>>>(in_proj_w, wtin, DM, 4096);
  transpose_bf16<<<dim3(1024 / 32, 2048 / 32), 256, 0, stream>>>(out_proj_w, wtout, DI, DM);
  // 1. LayerNorm -> bf16
  ln_kernel<<<NROWS, 256, 0, stream>>>(x, ln_w, ln_b, xnb);
  // 2. in_proj: xz = xn @ W  (M=4096,N=4096,K=1024) MFMA
  gemm_mfma<0><<<dim3(32, 32), 256, 0, stream>>>(xnb, wtin, xz, NROWS, 4096, DM, nullptr);
  // 3. depthwise conv + silu -> xc
  conv_silu_kernel<<<8192, 256, 0, stream>>>(xz, conv_w, conv_b, xc);
  // 4. x_proj split-K: part = xc @ x_proj_w, then reduce -> dbc
  xproj_splitk<<<dim3(XKS, 64), 256, 0, stream>>>(xc, x_proj_w, part);
  xproj_reduce<<<(NROWS * 96) / 256, 256, 0, stream>>>(part, dbc);
  // 5. dt_proj + softplus (K=64) fp32
  gemm_kernel<1><<<dim3(32, 64), 256, 0, stream>>>(dbc, dt_proj_w, dtb,
      NROWS, DI, DTR, 96, DI, 4096, dt_proj_b);
  // 6. chunked selective scan (register-state) -> y bf16
  scan_pass1<<<2 * NCHUNK * 8, 256, 0, stream>>>(dtb, xc, dbc, A_log, aprod, hout);
  scan_fixup<<<256, 256, 0, stream>>>(aprod, hout);
  scan_pass2<<<2 * NCHUNK * 8, 256, 0, stream>>>(dtb, xc, dbc, A_log, D_skip, zp, hout, yb16);
  // 7. out_proj + residual: out = x + y @ out_proj_w  (N=1024, K=2048) MFMA
  gemm_mfma<2><<<dim3(8, 32), 256, 0, stream>>>(yb16, wtout, out, NROWS, DM, DI, x);
}

// Round 11
// 406.561 us; speedup vs baseline: 4.1330x; 1.0037x over previous
//
#include <hip/hip_runtime.h>
#include <math.h>

#define NROWS 4096   // BATCH*SEQ
#define DM    1024   // D_MODEL
#define DI    2048   // D_INNER
#define DTR   64     // DT_RANK
#define DST   16     // D_STATE
#define NCHUNK 32
#define CHLEN  64    // 2048 / NCHUNK
#define XKS   8      // x_proj K-splits
#define XKL   256    // 2048 / XKS

typedef __attribute__((ext_vector_type(8))) short bf16x8;
typedef __attribute__((ext_vector_type(4))) float f32x4;

__device__ __forceinline__ unsigned short f2bf(float f) {
  unsigned u = __float_as_uint(f);
  u = (u + 0x7fffu + ((u >> 16) & 1u)) >> 16;   // RNE
  return (unsigned short)u;
}
__device__ __forceinline__ float softplus_f(float v) {
  return fmaxf(v, 0.f) + log1pf(__expf(-fabsf(v)));
}
__device__ __forceinline__ float silu_f(float v) {
  return v * (1.f / (1.f + __expf(-v)));
}
__device__ __forceinline__ void gload_lds16(const void* g, void* l) {
  __builtin_amdgcn_global_load_lds(
      (const __attribute__((address_space(1))) void*)g,
      (__attribute__((address_space(3))) void*)l, 16, 0, 0);
}

// ---------------------------------------------------------------- LayerNorm -> bf16
__global__ __launch_bounds__(256) void ln_kernel(const float* __restrict__ x,
                                                 const float* __restrict__ w,
                                                 const float* __restrict__ b,
                                                 unsigned short* __restrict__ xnb) {
  const int row = blockIdx.x;
  const int tid = threadIdx.x;
  const float4 v = ((const float4*)(x + (size_t)row * DM))[tid];
  float s  = v.x + v.y + v.z + v.w;
  float ss = v.x * v.x + v.y * v.y + v.z * v.z + v.w * v.w;
  for (int off = 32; off > 0; off >>= 1) {
    s  += __shfl_down(s, off);
    ss += __shfl_down(ss, off);
  }
  __shared__ float red[4][2];
  if ((tid & 63) == 0) { red[tid >> 6][0] = s; red[tid >> 6][1] = ss; }
  __syncthreads();
  const float fs  = red[0][0] + red[1][0] + red[2][0] + red[3][0];
  const float fss = red[0][1] + red[1][1] + red[2][1] + red[3][1];
  const float mu  = fs * (1.f / DM);
  const float var = fss * (1.f / DM) - mu * mu;
  const float rs  = rsqrtf(var + 1e-5f);
  const float4 wv = ((const float4*)w)[tid];
  const float4 bv = ((const float4*)b)[tid];
  ushort4 o;
  o.x = f2bf((v.x - mu) * rs * wv.x + bv.x);
  o.y = f2bf((v.y - mu) * rs * wv.y + bv.y);
  o.z = f2bf((v.z - mu) * rs * wv.z + bv.z);
  o.w = f2bf((v.w - mu) * rs * wv.w + bv.w);
  ((ushort4*)(xnb + (size_t)row * DM))[tid] = o;
}

// ---------------------------------------------------------------- W[K][N] f32 -> Wt[N][K] bf16
__global__ __launch_bounds__(256) void transpose_bf16(const float* __restrict__ W,
                                                      unsigned short* __restrict__ Wt,
                                                      int K, int N) {
  __shared__ float t[32][33];
  const int n0 = blockIdx.x * 32, k0 = blockIdx.y * 32;
  const int tx = threadIdx.x & 31, ty = threadIdx.x >> 5;  // ty 0..7
#pragma unroll
  for (int i = 0; i < 4; i++)
    t[ty + i * 8][tx] = W[(size_t)(k0 + ty + i * 8) * N + n0 + tx];
  __syncthreads();
#pragma unroll
  for (int i = 0; i < 4; i++)
    Wt[(size_t)(n0 + ty + i * 8) * K + k0 + tx] = f2bf(t[tx][ty + i * 8]);
}

// ---------------------------------------------------------------- bf16 MFMA GEMM
// C[M,N] = A[M,K](bf16) @ Bt[N,K](bf16)^T; 128x128 tile, BK=32, 4 waves 2x2.
template <int EPI>   // 0 none, 2 acc + resid
__global__ __launch_bounds__(256) void gemm_mfma(
    const unsigned short* __restrict__ A, const unsigned short* __restrict__ Bt,
    float* __restrict__ C, int M, int N, int K, const float* __restrict__ resid) {
  __shared__ unsigned short Asl[128 * 32];
  __shared__ unsigned short Bsl[128 * 32];
  const int tid  = threadIdx.x;
  const int wave = tid >> 6, lane = tid & 63;
  const int wr = wave >> 1, wc = wave & 1;
  const int m0 = blockIdx.y * 128, n0 = blockIdx.x * 128;
  const int srow = lane >> 2;
  const int skoff = (lane & 3) * 8;
  f32x4 acc[4][4] = {};
  for (int k0 = 0; k0 < K; k0 += 32) {
    __syncthreads();
#pragma unroll
    for (int i = 0; i < 2; i++) {
      const int c = wave * 2 + i;
      gload_lds16(A  + (size_t)(m0 + c * 16 + srow) * K + k0 + skoff, &Asl[c * 512]);
      gload_lds16(Bt + (size_t)(n0 + c * 16 + srow) * K + k0 + skoff, &Bsl[c * 512]);
    }
    __syncthreads();
    bf16x8 af[4], bfr[4];
#pragma unroll
    for (int m = 0; m < 4; m++)
      af[m] = *(const bf16x8*)&Asl[(wr * 64 + m * 16 + (lane & 15)) * 32 + (lane >> 4) * 8];
#pragma unroll
    for (int n = 0; n < 4; n++)
      bfr[n] = *(const bf16x8*)&Bsl[(wc * 64 + n * 16 + (lane & 15)) * 32 + (lane >> 4) * 8];
#pragma unroll
    for (int m = 0; m < 4; m++)
#pragma unroll
      for (int n = 0; n < 4; n++)
        acc[m][n] = __builtin_amdgcn_mfma_f32_16x16x32_bf16(af[m], bfr[n], acc[m][n], 0, 0, 0);
  }
#pragma unroll
  for (int m = 0; m < 4; m++) {
#pragma unroll
    for (int n = 0; n < 4; n++) {
      const int col = n0 + wc * 64 + n * 16 + (lane & 15);
#pragma unroll
      for (int r = 0; r < 4; r++) {
        const int row = m0 + wr * 64 + m * 16 + (lane >> 4) * 4 + r;
        float v = acc[m][n][r];
        if (EPI == 2) v += resid[(size_t)row * N + col];
        C[(size_t)row * N + col] = v;
      }
    }
  }
}

// ---------------------------------------------------------------- x_proj split-K
__global__ __launch_bounds__(256) void xproj_splitk(
    const float* __restrict__ A,   // xc [4096][2048]
    const float* __restrict__ B,   // x_proj_w [2048][96]
    float* __restrict__ part) {
  __shared__ float AsT[32][68];
  __shared__ float Bs[32][96];
  const int ks = blockIdx.x;       // 0..7
  const int r0 = blockIdx.y * 64;
  const int tid = threadIdx.x;
  const int rg = tid >> 4;
  const int cg = tid & 15;
  const int arow = tid >> 2;
  const int ac   = (tid & 3) * 2;
  const int bk   = tid >> 3;
  const int bc   = tid & 7;
  float acc[4][6] = {};
  const int k0base = ks * XKL;
  for (int kt = 0; kt < XKL; kt += 32) {
    const int k0 = k0base + kt;
    const float4 a0 = *(const float4*)&A[(size_t)(r0 + arow) * DI + k0 + ac * 4];
    const float4 a1 = *(const float4*)&A[(size_t)(r0 + arow) * DI + k0 + (ac + 1) * 4];
    const float4 b0 = *(const float4*)&B[(size_t)(k0 + bk) * 96 + bc * 4];
    const float4 b1 = *(const float4*)&B[(size_t)(k0 + bk) * 96 + (bc + 8) * 4];
    const float4 b2 = *(const float4*)&B[(size_t)(k0 + bk) * 96 + (bc + 16) * 4];
    __syncthreads();
#pragma unroll
    for (int j = 0; j < 4; j++) AsT[ac * 4 + j][arow] = (&a0.x)[j];
#pragma unroll
    for (int j = 0; j < 4; j++) AsT[(ac + 1) * 4 + j][arow] = (&a1.x)[j];
    *(float4*)&Bs[bk][bc * 4] = b0;
    *(float4*)&Bs[bk][(bc + 8) * 4] = b1;
    *(float4*)&Bs[bk][(bc + 16) * 4] = b2;
    __syncthreads();
#pragma unroll
    for (int k = 0; k < 32; k++) {
      const float4 av = *(const float4*)&AsT[k][rg * 4];
      const float2 bv0 = *(const float2*)&Bs[k][cg * 6];
      const float2 bv1 = *(const float2*)&Bs[k][cg * 6 + 2];
      const float2 bv2 = *(const float2*)&Bs[k][cg * 6 + 4];
#pragma unroll
      for (int i = 0; i < 4; i++) {
        const float a = (&av.x)[i];
        acc[i][0] += a * bv0.x; acc[i][1] += a * bv0.y;
        acc[i][2] += a * bv1.x; acc[i][3] += a * bv1.y;
        acc[i][4] += a * bv2.x; acc[i][5] += a * bv2.y;
      }
    }
  }
#pragma unroll
  for (int i = 0; i < 4; i++) {
    const int row = r0 + rg * 4 + i;
    float* p = &part[((size_t)ks * NROWS + row) * 96 + cg * 6];
#pragma unroll
    for (int j = 0; j < 3; j++)
      *(float2*)&p[j * 2] = make_float2(acc[i][j * 2], acc[i][j * 2 + 1]);
  }
}

__global__ __launch_bounds__(256) void xproj_reduce(const float* __restrict__ part,
                                                    float* __restrict__ dbc) {
  const int i = blockIdx.x * 256 + threadIdx.x;
  float s = 0.f;
#pragma unroll
  for (int ks = 0; ks < XKS; ks++) s += part[(size_t)ks * (NROWS * 96) + i];
  dbc[i] = s;
}

// ---------------------------------------------------------------- generic fp32 GEMM (dt_proj)
template <int EPI>  // 1: softplus(acc + bias[n])
__global__ __launch_bounds__(256) void gemm_kernel(
    const float* __restrict__ A, const float* __restrict__ B,
    float* __restrict__ C, int M, int N, int K, int lda, int ldb, int ldc,
    const float* __restrict__ bias) {
  __shared__ float As[64][20];
  __shared__ float Bs[16][64];
  const int tid = threadIdx.x;
  const int m0 = blockIdx.y * 64, n0 = blockIdx.x * 64;
  const int tx = tid & 15, ty = tid >> 4;
  const int am = tid >> 2, ak4 = (tid & 3) << 2;
  const int bk = tid >> 4, bn4 = (tid & 15) << 2;
  const bool bin = (n0 + bn4) < N;
  float acc[4][4] = {};
  for (int k0 = 0; k0 < K; k0 += 16) {
    const float4 av = *(const float4*)&A[(size_t)(m0 + am) * lda + k0 + ak4];
    float4 bv = make_float4(0.f, 0.f, 0.f, 0.f);
    if (bin) bv = *(const float4*)&B[(size_t)(k0 + bk) * ldb + n0 + bn4];
    __syncthreads();
    *(float4*)&As[am][ak4] = av;
    *(float4*)&Bs[bk][bn4] = bv;
    __syncthreads();
#pragma unroll
    for (int k4 = 0; k4 < 4; k4++) {
      float4 aa[4], bb[4];
#pragma unroll
      for (int i = 0; i < 4; i++) aa[i] = *(const float4*)&As[ty * 4 + i][k4 * 4];
#pragma unroll
      for (int kk = 0; kk < 4; kk++) bb[kk] = *(const float4*)&Bs[k4 * 4 + kk][tx * 4];
#pragma unroll
      for (int kk = 0; kk < 4; kk++) {
#pragma unroll
        for (int i = 0; i < 4; i++) {
          const float a = (&aa[i].x)[kk];
          acc[i][0] += a * bb[kk].x;
          acc[i][1] += a * bb[kk].y;
          acc[i][2] += a * bb[kk].z;
          acc[i][3] += a * bb[kk].w;
        }
      }
    }
  }
#pragma unroll
  for (int i = 0; i < 4; i++) {
    const int row = m0 + ty * 4 + i;
    const int col = n0 + tx * 4;
    if (col < N) {
      float4 o = make_float4(acc[i][0], acc[i][1], acc[i][2], acc[i][3]);
      if (EPI == 1) {
        const float4 bi = *(const float4*)&bias[col];
        o.x = softplus_f(o.x + bi.x);
        o.y = softplus_f(o.y + bi.y);
        o.z = softplus_f(o.z + bi.z);
        o.w = softplus_f(o.w + bi.w);
      }
      *(float4*)&C[(size_t)row * ldc + col] = o;
    }
  }
}

// ---------------------------------------------------------------- depthwise causal conv + SiLU
__global__ __launch_bounds__(256) void conv_silu_kernel(const float* __restrict__ xz,
                                                        const float* __restrict__ cw,
                                                        const float* __restrict__ cb,
                                                        float* __restrict__ xc) {
  const int idx = blockIdx.x * 256 + threadIdx.x;
  const int d4 = (idx & 511) << 2;
  const int r = idx >> 9;
  const int t = r & 2047;
  const float4 w0 = *(const float4*)&cw[(d4 + 0) * 4];
  const float4 w1 = *(const float4*)&cw[(d4 + 1) * 4];
  const float4 w2 = *(const float4*)&cw[(d4 + 2) * 4];
  const float4 w3 = *(const float4*)&cw[(d4 + 3) * 4];
  float4 acc = *(const float4*)&cb[d4];
#pragma unroll
  for (int j = 0; j < 4; j++) {
    const int tj = t - 3 + j;
    if (tj >= 0) {
      const float4 xv = *(const float4*)&xz[(size_t)(r - 3 + j) * 4096 + d4];
      acc.x += xv.x * (&w0.x)[j];
      acc.y += xv.y * (&w1.x)[j];
      acc.z += xv.z * (&w2.x)[j];
      acc.w += xv.w * (&w3.x)[j];
    }
  }
  acc.x = silu_f(acc.x); acc.y = silu_f(acc.y);
  acc.z = silu_f(acc.z); acc.w = silu_f(acc.w);
  *(float4*)&xc[(size_t)r * DI + d4] = acc;
}

// ---------------------------------------------------------------- chunked selective scan
// State-split register layout: thread pair = (channel d, state-half sh); 8 states/thread
// in VGPRs. grid: 2(b) x 32(c) x 16(dgrp) = 1024 blocks (4/CU, ~16 waves/CU).
// Paired lanes load the same dt/xc/z word (HW broadcast) -> no extra HBM traffic.
// Carries keep the [b][c][s][d] layout -> fixup unchanged.
__global__ __launch_bounds__(256) void scan_pass1(
    const float* __restrict__ dt,    // ld 4096
    const float* __restrict__ xc,    // ld 2048
    const float* __restrict__ dbc,   // ld 96; B at +64
    const float* __restrict__ A_log,
    float* __restrict__ aprod_buf, float* __restrict__ hout_buf) {
  const int bx = blockIdx.x;
  const int b = bx >> 9, c = (bx >> 4) & 31, dgrp = bx & 15;
  const int tid = threadIdx.x;
  const int d  = dgrp * 128 + (tid >> 1);
  const int sh = (tid & 1) * 8;            // states [sh, sh+8)
  float A[8], h[8], ap[8];
#pragma unroll
  for (int j = 0; j < 8; j++) {
    A[j] = -expf(A_log[d * DST + sh + j]);
    h[j] = 0.f; ap[j] = 1.f;
  }
  const int base_r = b * 2048 + c * CHLEN;
#pragma unroll 2
  for (int t = 0; t < CHLEN; t++) {
    const size_t r = base_r + t;
    const float dtv = dt[r * 4096 + d];
    const float uv  = xc[r * 2048 + d];
    const float du = dtv * uv;
    const float* bc = &dbc[r * 96 + DTR + sh];
#pragma unroll
    for (int j = 0; j < 8; j++) {
      const float a = __expf(dtv * A[j]);
      h[j] = a * h[j] + du * bc[j];
      ap[j] *= a;
    }
  }
  const size_t base = ((size_t)(b * NCHUNK + c) * DST) * DI + d;
#pragma unroll
  for (int j = 0; j < 8; j++) {
    aprod_buf[base + (size_t)(sh + j) * DI] = ap[j];
    hout_buf[base + (size_t)(sh + j) * DI]  = h[j];
  }
}

// fixup: thread = (b,s,d); folds NCHUNK chunk carries -> per-chunk h_in (overwrites hout)
__global__ __launch_bounds__(256) void scan_fixup(const float* __restrict__ aprod_buf,
                                                  float* __restrict__ hout_buf) {
  const int gl = blockIdx.x * 256 + threadIdx.x;  // 65536
  const int d = gl & 2047, s = (gl >> 11) & 15, b = gl >> 15;
  const size_t base = ((size_t)(b * NCHUNK) * DST + s) * DI + d;
  const size_t stride = (size_t)DST * DI;
  float h = 0.f;
#pragma unroll
  for (int c = 0; c < NCHUNK; c++) {
    const float a = aprod_buf[base + c * stride];
    const float o = hout_buf[base + c * stride];
    hout_buf[base + c * stride] = h;
    h = a * h + o;
  }
}

// pass2: re-run chunk from h_in; y = (scan_y + xc*Dskip) * silu(z) -> bf16
__global__ __launch_bounds__(256) void scan_pass2(
    const float* __restrict__ dt, const float* __restrict__ xc,
    const float* __restrict__ dbc, const float* __restrict__ A_log,
    const float* __restrict__ Dskip, const float* __restrict__ z,
    const float* __restrict__ hin_buf, unsigned short* __restrict__ y16) {
  const int bx = blockIdx.x;
  const int b = bx >> 9, c = (bx >> 4) & 31, dgrp = bx & 15;
  const int tid = threadIdx.x;
  const int d  = dgrp * 128 + (tid >> 1);
  const int sh = (tid & 1) * 8;
  float A[8], h[8];
  const size_t base = ((size_t)(b * NCHUNK + c) * DST) * DI + d;
#pragma unroll
  for (int j = 0; j < 8; j++) {
    A[j] = -expf(A_log[d * DST + sh + j]);
    h[j] = hin_buf[base + (size_t)(sh + j) * DI];
  }
  const float dsk = Dskip[d];
  const int base_r = b * 2048 + c * CHLEN;
#pragma unroll 2
  for (int t = 0; t < CHLEN; t++) {
    const size_t r = base_r + t;
    const float dtv = dt[r * 4096 + d];
    const float uv  = xc[r * 2048 + d];
    const float zv  = z[r * 4096 + d];
    const float du = dtv * uv;
    const float* bc = &dbc[r * 96 + DTR + sh];       // B half
    const float* cc = &dbc[r * 96 + DTR + DST + sh]; // C half
    float p = 0.f;
#pragma unroll
    for (int j = 0; j < 8; j++) {
      const float a = __expf(dtv * A[j]);
      h[j] = a * h[j] + du * bc[j];
      p += h[j] * cc[j];
    }
    p += __shfl_xor(p, 1);   // combine the two state-halves
    if ((tid & 1) == 0) {
      const float y = (p + uv * dsk) * silu_f(zv);
      y16[r * 2048 + d] = f2bf(y);
    }
  }
}

// ---------------------------------------------------------------- launch
extern "C" void kernel_launch(void* const* d_in, const int* in_sizes, int n_in,
                              void* d_out, int out_size, void* d_ws, size_t ws_size,
                              hipStream_t stream) {
  const float* x         = (const float*)d_in[0];
  const float* ln_w      = (const float*)d_in[1];
  const float* ln_b      = (const float*)d_in[2];
  const float* in_proj_w = (const float*)d_in[3];
  const float* conv_w    = (const float*)d_in[4];
  const float* conv_b    = (const float*)d_in[5];
  const float* x_proj_w  = (const float*)d_in[6];
  const float* dt_proj_w = (const float*)d_in[7];
  const float* dt_proj_b = (const float*)d_in[8];
  const float* A_log     = (const float*)d_in[9];
  const float* D_skip    = (const float*)d_in[10];
  const float* out_proj_w= (const float*)d_in[11];
  float* out = (float*)d_out;
  float* ws  = (float*)d_ws;

  unsigned short* xnb  = (unsigned short*)ws;          // [0, 2M floats) live steps 1-2
  float* part  = ws;                                   // [0, 3M) x_proj partials (step 4; xnb dead)
  float* aprod = ws;                                   // [0, 2M) carries (step 6; part dead)
  float* hout  = ws + (2u << 20);                      // [2M, 4M)
  float* xz    = ws + (4u << 20);                      // [4M, 20M)
  float* xc    = ws + (20u << 20);                     // [20M, 28M)
  float* dbc   = ws + (28u << 20);                     // [28M, +0.375M)
  unsigned short* wtin  = (unsigned short*)(ws + (29u << 20));  // 4096x1024 bf16
  unsigned short* wtout = (unsigned short*)(ws + (31u << 20));  // 1024x2048 bf16
  unsigned short* yb16  = (unsigned short*)(ws + (32u << 20));  // 4096x2048 bf16
  float* dtb = xz;          // dt overwrites xi in place (ld 4096)
  float* zp  = xz + DI;     // z (ld 4096)

  // 0. weight transpose+convert: Wt[N][K] bf16
  transpose_bf16<<<dim3(4096 / 32, 1024 / 32), 256, 0, stream>>>(in_proj_w, wtin, DM, 4096);
  transpose_bf16<<<dim3(1024 / 32, 2048 / 32), 256, 0, stream>>>(out_proj_w, wtout, DI, DM);
  // 1. LayerNorm -> bf16
  ln_kernel<<<NROWS, 256, 0, stream>>>(x, ln_w, ln_b, xnb);
  // 2. in_proj: xz = xn @ W  (M=4096,N=4096,K=1024) MFMA
  gemm_mfma<0><<<dim3(32, 32), 256, 0, stream>>>(xnb, wtin, xz, NROWS, 4096, DM, nullptr);
  // 3. depthwise conv + silu -> xc
  conv_silu_kernel<<<8192, 256, 0, stream>>>(xz, conv_w, conv_b, xc);
  // 4. x_proj split-K: part = xc @ x_proj_w, then reduce -> dbc
  xproj_splitk<<<dim3(XKS, 64), 256, 0, stream>>>(xc, x_proj_w, part);
  xproj_reduce<<<(NROWS * 96) / 256, 256, 0, stream>>>(part, dbc);
  // 5. dt_proj + softplus (K=64) fp32
  gemm_kernel<1><<<dim3(32, 64), 256, 0, stream>>>(dbc, dt_proj_w, dtb,
      NROWS, DI, DTR, 96, DI, 4096, dt_proj_b);
  // 6. chunked selective scan (state-split register) -> y bf16
  scan_pass1<<<2 * NCHUNK * 16, 256, 0, stream>>>(dtb, xc, dbc, A_log, aprod, hout);
  scan_fixup<<<256, 256, 0, stream>>>(aprod, hout);
  scan_pass2<<<2 * NCHUNK * 16, 256, 0, stream>>>(dtb, xc, dbc, A_log, D_skip, zp, hout, yb16);
  // 7. out_proj + residual: out = x + y @ out_proj_w  (N=1024, K=2048) MFMA
  gemm_mfma<2><<<dim3(8, 32), 256, 0, stream>>>(yb16, wtout, out, NROWS, DM, DI, x);
}